// Round 1
// baseline (1225.586 us; speedup 1.0000x reference)
//
#include <hip/hip_runtime.h>
#include <math.h>

#define D_MODEL 1024
#define N_HEADS 16
#define HEAD_DIM 64
#define BATCH 2
#define SEQ 2048
#define TOKENS (BATCH * SEQ)   // 4096

// ---------------------------------------------------------------------------
// Generic fp32 GEMM with bias: C[M,N] = A[M,K] @ B[K,N] + bias[N]
// 128x128 block tile, BK=8, 256 threads, 8x8 microtile per thread.
// ---------------------------------------------------------------------------
#define BM 128
#define BN 128
#define BK 8

__global__ __launch_bounds__(256) void gemm_bias_kernel(
    const float* __restrict__ A, const float* __restrict__ Bm,
    const float* __restrict__ bias, float* __restrict__ C,
    int M, int N, int K)
{
    __shared__ float As[BK][BM];   // transposed A tile
    __shared__ float Bs[BK][BN];

    const int tid = threadIdx.x;
    const int m0 = blockIdx.y * BM;
    const int n0 = blockIdx.x * BN;

    const int arow = tid >> 1;          // 0..127
    const int acol = (tid & 1) * 4;     // 0 or 4
    const int brow = tid >> 5;          // 0..7
    const int bcol = (tid & 31) * 4;    // 0..124

    const int ty = tid >> 4;            // 0..15
    const int tx = tid & 15;            // 0..15

    float acc[8][8];
#pragma unroll
    for (int i = 0; i < 8; ++i)
#pragma unroll
        for (int j = 0; j < 8; ++j) acc[i][j] = 0.f;

    const float* Aptr = A + (size_t)(m0 + arow) * K + acol;
    const float* Bptr = Bm + (size_t)brow * N + n0 + bcol;

    for (int k0 = 0; k0 < K; k0 += BK) {
        float4 av = *(const float4*)(Aptr + k0);
        float4 bv = *(const float4*)(Bptr + (size_t)k0 * N);
        As[acol + 0][arow] = av.x;
        As[acol + 1][arow] = av.y;
        As[acol + 2][arow] = av.z;
        As[acol + 3][arow] = av.w;
        *(float4*)&Bs[brow][bcol] = bv;
        __syncthreads();

#pragma unroll
        for (int kk = 0; kk < BK; ++kk) {
            float ar[8], br[8];
            *(float4*)&ar[0] = *(const float4*)&As[kk][ty * 8];
            *(float4*)&ar[4] = *(const float4*)&As[kk][ty * 8 + 4];
            *(float4*)&br[0] = *(const float4*)&Bs[kk][tx * 8];
            *(float4*)&br[4] = *(const float4*)&Bs[kk][tx * 8 + 4];
#pragma unroll
            for (int i = 0; i < 8; ++i)
#pragma unroll
                for (int j = 0; j < 8; ++j)
                    acc[i][j] += ar[i] * br[j];
        }
        __syncthreads();
    }

    float4 bv0 = *(const float4*)&bias[n0 + tx * 8];
    float4 bv1 = *(const float4*)&bias[n0 + tx * 8 + 4];
#pragma unroll
    for (int i = 0; i < 8; ++i) {
        float* cp = C + (size_t)(m0 + ty * 8 + i) * N + n0 + tx * 8;
        float4 o0, o1;
        o0.x = acc[i][0] + bv0.x; o0.y = acc[i][1] + bv0.y;
        o0.z = acc[i][2] + bv0.z; o0.w = acc[i][3] + bv0.w;
        o1.x = acc[i][4] + bv1.x; o1.y = acc[i][5] + bv1.y;
        o1.z = acc[i][6] + bv1.z; o1.w = acc[i][7] + bv1.w;
        *(float4*)cp = o0;
        *(float4*)(cp + 4) = o1;
    }
}

// ---------------------------------------------------------------------------
// RoPE applied in-place to q and k halves of the qkv buffer.
// qkv layout: [token, 3*D_MODEL]; q at col h*64+d, k at +1024.
// One thread per (token, head, pair).
// ---------------------------------------------------------------------------
__global__ __launch_bounds__(256) void rope_kernel(float* __restrict__ qkv)
{
    int gid = blockIdx.x * 256 + threadIdx.x;   // 0 .. 4096*16*32-1
    int p = gid & 31;          // pair index 0..31
    int h = (gid >> 5) & 15;   // head
    int token = gid >> 9;      // 0..4095
    int t = token & (SEQ - 1); // position in sequence

    // inv_freq = 10000^(-2p/64), computed in double then rounded (<=1ulp of ref)
    double e = (double)(2 * p) / 64.0;
    float inv = (float)exp2(-e * 13.287712379549449); // log2(10000)
    float ang = (float)t * inv;
    float s, c;
    __sincosf(ang, &s, &c);

    size_t base = (size_t)token * (3 * D_MODEL) + h * HEAD_DIM + 2 * p;
    float qe = qkv[base], qo = qkv[base + 1];
    qkv[base]     = qe * c - qo * s;
    qkv[base + 1] = qe * s + qo * c;
    size_t kb = base + D_MODEL;
    float ke = qkv[kb], ko = qkv[kb + 1];
    qkv[kb]     = ke * c - ko * s;
    qkv[kb + 1] = ke * s + ko * c;
}

// ---------------------------------------------------------------------------
// Flash attention (causal + padding mask), fp32.
// Grid: (qt=0..31, bh=0..31). Block 256 threads.
// Q tile 64 rows, KV tile 32 rows, head dim 64.
// Thread (ty,tx): rows ty*4+i; S/P cols tx+16j (j=0..1); O dims tx*4+j.
// ---------------------------------------------------------------------------
#define QT 64
#define KT 32
#define LDQ 68
#define LDK 68
#define LDV 68
#define LDP 36

__global__ __launch_bounds__(256) void flash_attn_kernel(
    const float* __restrict__ qkv, const int* __restrict__ am,
    float* __restrict__ attn)
{
    __shared__ float Qs[QT][LDQ];
    __shared__ float Ks[KT][LDK];
    __shared__ float Vs[KT][LDV];
    __shared__ float Ps[QT][LDP];

    const int tid = threadIdx.x;
    const int qt = blockIdx.x;
    const int bh = blockIdx.y;
    const int b = bh >> 4, h = bh & 15;
    const int ty = tid >> 4, tx = tid & 15;
    const int ty4 = ty * 4;
    const float scale = 0.125f;   // 1/sqrt(64)

    // ---- load Q tile (scaled) ----
    {
        int r = tid >> 2;
        int cq = (tid & 3) * 4;
        const float* src = qkv + (size_t)(b * SEQ + qt * QT + r) * (3 * D_MODEL)
                         + h * HEAD_DIM + cq;
#pragma unroll
        for (int m = 0; m < 4; ++m) {
            float4 v = *(const float4*)(src + 16 * m);
            float4 w;
            w.x = v.x * scale; w.y = v.y * scale;
            w.z = v.z * scale; w.w = v.w * scale;
            *(float4*)&Qs[r][cq + 16 * m] = w;
        }
    }

    float m_[4], l_[4], o_[4][4];
#pragma unroll
    for (int i = 0; i < 4; ++i) {
        m_[i] = -INFINITY; l_[i] = 0.f;
#pragma unroll
        for (int j = 0; j < 4; ++j) o_[i][j] = 0.f;
    }

    const int ktiles = 2 * qt + 2;
    // KV load indices
    const int lr = tid >> 3;          // 0..31
    const int lc = (tid & 7) * 4;     // 0..28

    for (int kt = 0; kt < ktiles; ++kt) {
        __syncthreads();   // protect Ks/Vs vs previous PV reads (and Qs load 1st iter)
        {
            const float* kb = qkv + (size_t)(b * SEQ + kt * KT + lr) * (3 * D_MODEL)
                            + D_MODEL + h * HEAD_DIM + lc;
            const float* vb = kb + D_MODEL;
            *(float4*)&Ks[lr][lc]      = *(const float4*)(kb);
            *(float4*)&Ks[lr][lc + 32] = *(const float4*)(kb + 32);
            *(float4*)&Vs[lr][lc]      = *(const float4*)(vb);
            *(float4*)&Vs[lr][lc + 32] = *(const float4*)(vb + 32);
        }
        __syncthreads();

        // ---- S = Q K^T (scaled) ----
        float s0[4], s1[4];
#pragma unroll
        for (int i = 0; i < 4; ++i) { s0[i] = 0.f; s1[i] = 0.f; }
#pragma unroll
        for (int d4 = 0; d4 < 16; ++d4) {
            float4 k0 = *(const float4*)&Ks[tx][d4 * 4];
            float4 k1 = *(const float4*)&Ks[tx + 16][d4 * 4];
#pragma unroll
            for (int i = 0; i < 4; ++i) {
                float4 q = *(const float4*)&Qs[ty4 + i][d4 * 4];
                s0[i] += q.x * k0.x + q.y * k0.y + q.z * k0.z + q.w * k0.w;
                s1[i] += q.x * k1.x + q.y * k1.y + q.z * k1.z + q.w * k1.w;
            }
        }

        // ---- mask ----
        const int cg0 = kt * KT + tx;
        const int cg1 = cg0 + 16;
        const int ok0m = am[b * SEQ + cg0];
        const int ok1m = am[b * SEQ + cg1];
#pragma unroll
        for (int i = 0; i < 4; ++i) {
            int rg = qt * QT + ty4 + i;
            if (cg0 > rg || !ok0m) s0[i] = -INFINITY;
            if (cg1 > rg || !ok1m) s1[i] = -INFINITY;
        }

        // ---- online softmax ----
#pragma unroll
        for (int i = 0; i < 4; ++i) {
            float mx = fmaxf(s0[i], s1[i]);
            mx = fmaxf(mx, __shfl_xor(mx, 1, 16));
            mx = fmaxf(mx, __shfl_xor(mx, 2, 16));
            mx = fmaxf(mx, __shfl_xor(mx, 4, 16));
            mx = fmaxf(mx, __shfl_xor(mx, 8, 16));
            float mnew = fmaxf(m_[i], mx);
            float alpha, p0, p1;
            if (mnew == -INFINITY) {
                alpha = 1.f; p0 = 0.f; p1 = 0.f;
            } else {
                alpha = __expf(m_[i] - mnew);   // m_=-inf -> 0
                p0 = __expf(s0[i] - mnew);      // s=-inf -> 0
                p1 = __expf(s1[i] - mnew);
            }
            float rs = p0 + p1;
            rs += __shfl_xor(rs, 1, 16);
            rs += __shfl_xor(rs, 2, 16);
            rs += __shfl_xor(rs, 4, 16);
            rs += __shfl_xor(rs, 8, 16);
            l_[i] = l_[i] * alpha + rs;
            m_[i] = mnew;
#pragma unroll
            for (int j = 0; j < 4; ++j) o_[i][j] *= alpha;
            Ps[ty4 + i][tx] = p0;
            Ps[ty4 + i][tx + 16] = p1;
        }
        __syncthreads();

        // ---- O += P @ V ----
#pragma unroll
        for (int k4 = 0; k4 < 8; ++k4) {
            float pr[4][4];
#pragma unroll
            for (int i = 0; i < 4; ++i)
                *(float4*)&pr[i][0] = *(const float4*)&Ps[ty4 + i][k4 * 4];
#pragma unroll
            for (int kk = 0; kk < 4; ++kk) {
                float4 v = *(const float4*)&Vs[k4 * 4 + kk][tx * 4];
#pragma unroll
                for (int i = 0; i < 4; ++i) {
                    o_[i][0] += pr[i][kk] * v.x;
                    o_[i][1] += pr[i][kk] * v.y;
                    o_[i][2] += pr[i][kk] * v.z;
                    o_[i][3] += pr[i][kk] * v.w;
                }
            }
        }
    }

    // ---- finalize and store ----
#pragma unroll
    for (int i = 0; i < 4; ++i) {
        float rl = 1.0f / l_[i];
        float4 o;
        o.x = o_[i][0] * rl; o.y = o_[i][1] * rl;
        o.z = o_[i][2] * rl; o.w = o_[i][3] * rl;
        float* dst = attn + (size_t)(b * SEQ + qt * QT + ty4 + i) * D_MODEL
                   + h * HEAD_DIM + tx * 4;
        *(float4*)dst = o;
    }
}

// ---------------------------------------------------------------------------
extern "C" void kernel_launch(void* const* d_in, const int* in_sizes, int n_in,
                              void* d_out, int out_size, void* d_ws, size_t ws_size,
                              hipStream_t stream)
{
    const float* x    = (const float*)d_in[0];
    const int*   am   = (const int*)d_in[1];
    const float* Wqkv = (const float*)d_in[2];
    const float* bqkv = (const float*)d_in[3];
    const float* Wout = (const float*)d_in[4];
    const float* bout = (const float*)d_in[5];
    float* out = (float*)d_out;

    float* qkv  = (float*)d_ws;                       // 4096 x 3072
    float* attn = qkv + (size_t)TOKENS * 3 * D_MODEL; // 4096 x 1024

    // 1) qkv = x @ W_qkv + b_qkv
    gemm_bias_kernel<<<dim3(3 * D_MODEL / BN, TOKENS / BM), 256, 0, stream>>>(
        x, Wqkv, bqkv, qkv, TOKENS, 3 * D_MODEL, D_MODEL);

    // 2) RoPE in place on q,k
    rope_kernel<<<(TOKENS * N_HEADS * 32) / 256, 256, 0, stream>>>(qkv);

    // 3) flash attention -> attn (B,T,D layout)
    flash_attn_kernel<<<dim3(SEQ / QT, BATCH * N_HEADS), 256, 0, stream>>>(
        qkv, am, attn);

    // 4) out = attn @ W_out + b_out
    gemm_bias_kernel<<<dim3(D_MODEL / BN, TOKENS / BM), 256, 0, stream>>>(
        attn, Wout, bout, out, TOKENS, D_MODEL, D_MODEL);
}

// Round 2
// 796.825 us; speedup vs baseline: 1.5381x; 1.5381x over previous
//
#include <hip/hip_runtime.h>
#include <math.h>
#include <stdint.h>

#define D_MODEL 1024
#define N_HEADS 16
#define HEAD_DIM 64
#define BATCH 2
#define SEQ 2048
#define TOKENS (BATCH * SEQ)   // 4096

typedef __attribute__((ext_vector_type(8))) short short8;   // 8 bf16 = 4 VGPRs (MFMA A/B frag)
typedef __attribute__((ext_vector_type(4))) float floatx4;  // MFMA C/D frag

// manual bf16 round-to-nearest-even (no header dependency on __hip_bfloat16 internals)
__device__ __forceinline__ unsigned short f2bf(float f) {
    uint32_t u = __float_as_uint(f);
    u += 0x7fffu + ((u >> 16) & 1u);
    return (unsigned short)(u >> 16);
}
__device__ __forceinline__ float bf2f(unsigned short h) {
    return __uint_as_float(((uint32_t)h) << 16);
}

// ---------------------------------------------------------------------------
// Weight transpose + bf16 hi/lo split:  W fp32 [1024][N]  ->  Bt bf16 [N][2048]
// Bt[n][k] = hi(W[k][n]),  Bt[n][1024+k] = lo(W[k][n])
// ---------------------------------------------------------------------------
__global__ __launch_bounds__(256) void split_w_t(
    const float* __restrict__ W, int N, unsigned short* __restrict__ Bt)
{
    __shared__ float t[32][33];
    const int tid = threadIdx.x;
    const int n0 = blockIdx.x * 32, k0 = blockIdx.y * 32;
    const int c = tid & 31, r = tid >> 5;  // r = 0..7
#pragma unroll
    for (int i = 0; i < 4; ++i)
        t[r + 8 * i][c] = W[(size_t)(k0 + r + 8 * i) * N + n0 + c];
    __syncthreads();
#pragma unroll
    for (int i = 0; i < 4; ++i) {
        int dn = r + 8 * i;
        float f = t[c][dn];                 // = W[k0+c][n0+dn]
        unsigned short hi = f2bf(f);
        unsigned short lo = f2bf(f - bf2f(hi));
        size_t row = (size_t)(n0 + dn) * 2048;
        Bt[row + k0 + c] = hi;
        Bt[row + 1024 + k0 + c] = lo;
    }
}

// ---------------------------------------------------------------------------
// bf16x3 MFMA GEMM: C[M,N] = A[M,1024] @ W[1024,N] + bias, fp32-grade accuracy.
// Virtual K' = 3072: k' in [0,1024) -> Ah*Bh, [1024,2048) -> Ah*Bl,
// [2048,3072) -> Al*Bh.  A converted fp32->bf16 hi/lo during LDS staging;
// Bt is the pre-split [N][2048] bf16 buffer.
// Tiles: BM x BN, BK=32, 256 threads = 4 waves of (FMx16) x (FNx16) MFMAs.
// ---------------------------------------------------------------------------
template<int BM, int BN, int WAVES_M, int WAVES_N, int FM, int FN>
__global__ __launch_bounds__(256) void gemm_x3(
    const float* __restrict__ A, const unsigned short* __restrict__ Bt,
    const float* __restrict__ bias, float* __restrict__ C, int M, int N)
{
    __shared__ __align__(16) short As[BM * 32];
    __shared__ __align__(16) short Bs[BN * 32];

    const int tid = threadIdx.x;
    const int m0 = blockIdx.y * BM, n0 = blockIdx.x * BN;
    const int w = tid >> 6, lane = tid & 63;
    const int l15 = lane & 15, q = lane >> 4;
    const int wm = w / WAVES_N, wn = w % WAVES_N;

    floatx4 acc[FM][FN];
#pragma unroll
    for (int fm = 0; fm < FM; ++fm)
#pragma unroll
        for (int fn = 0; fn < FN; ++fn) acc[fm][fn] = (floatx4)0.f;

    constexpr int NA = BM * 4 / 256;   // 16B LDS chunks of A per thread
    constexpr int NB = BN * 4 / 256;

    for (int k0 = 0; k0 < 3072; k0 += 32) {
        const int kk = k0 & 1023;                       // A source k
        const bool islo = (k0 >= 2048);                 // A uses lo part
        const int kB = (k0 < 2048) ? k0 : (k0 - 2048);  // Bt col (hi|lo layout)

        float4 fa[NA][2];
        uint4 vb[NB];
#pragma unroll
        for (int i = 0; i < NA; ++i) {
            int c = tid + i * 256, m = c >> 2, kb = c & 3;
            const float* gp = A + (size_t)(m0 + m) * 1024 + kk + kb * 8;
            fa[i][0] = *(const float4*)gp;
            fa[i][1] = *(const float4*)(gp + 4);
        }
#pragma unroll
        for (int i = 0; i < NB; ++i) {
            int c = tid + i * 256, n = c >> 2, kb = c & 3;
            vb[i] = *(const uint4*)(Bt + (size_t)(n0 + n) * 2048 + kB + kb * 8);
        }
        __syncthreads();   // previous iteration done reading LDS
#pragma unroll
        for (int i = 0; i < NA; ++i) {
            int c = tid + i * 256;
            float v[8];
            *(float4*)&v[0] = fa[i][0];
            *(float4*)&v[4] = fa[i][1];
            unsigned short u[8];
#pragma unroll
            for (int j = 0; j < 8; ++j) {
                unsigned short h = f2bf(v[j]);
                u[j] = islo ? f2bf(v[j] - bf2f(h)) : h;
            }
            uint4 wv;
            wv.x = (uint32_t)u[0] | ((uint32_t)u[1] << 16);
            wv.y = (uint32_t)u[2] | ((uint32_t)u[3] << 16);
            wv.z = (uint32_t)u[4] | ((uint32_t)u[5] << 16);
            wv.w = (uint32_t)u[6] | ((uint32_t)u[7] << 16);
            ((uint4*)As)[c] = wv;
        }
#pragma unroll
        for (int i = 0; i < NB; ++i) ((uint4*)Bs)[tid + i * 256] = vb[i];
        __syncthreads();

        short8 af[FM], bfr[FN];
#pragma unroll
        for (int fm = 0; fm < FM; ++fm)
            af[fm] = *(const short8*)(As + (wm * FM * 16 + fm * 16 + l15) * 32 + q * 8);
#pragma unroll
        for (int fn = 0; fn < FN; ++fn)
            bfr[fn] = *(const short8*)(Bs + (wn * FN * 16 + fn * 16 + l15) * 32 + q * 8);
#pragma unroll
        for (int fm = 0; fm < FM; ++fm)
#pragma unroll
            for (int fn = 0; fn < FN; ++fn)
                acc[fm][fn] = __builtin_amdgcn_mfma_f32_16x16x32_bf16(
                    af[fm], bfr[fn], acc[fm][fn], 0, 0, 0);
    }

    // epilogue: C/D layout col = lane&15, row = (lane>>4)*4 + reg  [m89/m91]
#pragma unroll
    for (int fm = 0; fm < FM; ++fm)
#pragma unroll
        for (int fn = 0; fn < FN; ++fn) {
            int col = n0 + (wn * FN + fn) * 16 + l15;
            float bv = bias[col];
#pragma unroll
            for (int r = 0; r < 4; ++r) {
                int row = m0 + (wm * FM + fm) * 16 + q * 4 + r;
                C[(size_t)row * N + col] = acc[fm][fn][r] + bv;
            }
        }
}

// ---------------------------------------------------------------------------
// RoPE applied in-place to q and k halves of the qkv buffer (unchanged, passing).
// ---------------------------------------------------------------------------
__global__ __launch_bounds__(256) void rope_kernel(float* __restrict__ qkv)
{
    int gid = blockIdx.x * 256 + threadIdx.x;
    int p = gid & 31;
    int h = (gid >> 5) & 15;
    int token = gid >> 9;
    int t = token & (SEQ - 1);

    double e = (double)(2 * p) / 64.0;
    float inv = (float)exp2(-e * 13.287712379549449); // log2(10000)
    float ang = (float)t * inv;
    float s, c;
    __sincosf(ang, &s, &c);

    size_t base = (size_t)token * (3 * D_MODEL) + h * HEAD_DIM + 2 * p;
    float qe = qkv[base], qo = qkv[base + 1];
    qkv[base]     = qe * c - qo * s;
    qkv[base + 1] = qe * s + qo * c;
    size_t kb = base + D_MODEL;
    float ke = qkv[kb], ko = qkv[kb + 1];
    qkv[kb]     = ke * c - ko * s;
    qkv[kb + 1] = ke * s + ko * c;
}

// ---------------------------------------------------------------------------
// Flash attention (causal + padding mask), fp32. Only change vs R1: linear
// grid with HEAVY-FIRST qt mapping so the 64-KV-tile blocks launch first.
// ---------------------------------------------------------------------------
#define QT 64
#define KT 32
#define LDQ 68
#define LDK 68
#define LDV 68
#define LDP 36

__global__ __launch_bounds__(256) void flash_attn_kernel(
    const float* __restrict__ qkv, const int* __restrict__ am,
    float* __restrict__ attn)
{
    __shared__ float Qs[QT][LDQ];
    __shared__ float Ks[KT][LDK];
    __shared__ float Vs[KT][LDV];
    __shared__ float Ps[QT][LDP];

    const int tid = threadIdx.x;
    const int lin = blockIdx.x;
    const int qt = 31 - (lin >> 5);   // heavy tiles dispatched first
    const int bh = lin & 31;
    const int b = bh >> 4, h = bh & 15;
    const int ty = tid >> 4, tx = tid & 15;
    const int ty4 = ty * 4;
    const float scale = 0.125f;

    {
        int r = tid >> 2;
        int cq = (tid & 3) * 4;
        const float* src = qkv + (size_t)(b * SEQ + qt * QT + r) * (3 * D_MODEL)
                         + h * HEAD_DIM + cq;
#pragma unroll
        for (int m = 0; m < 4; ++m) {
            float4 v = *(const float4*)(src + 16 * m);
            float4 w;
            w.x = v.x * scale; w.y = v.y * scale;
            w.z = v.z * scale; w.w = v.w * scale;
            *(float4*)&Qs[r][cq + 16 * m] = w;
        }
    }

    float m_[4], l_[4], o_[4][4];
#pragma unroll
    for (int i = 0; i < 4; ++i) {
        m_[i] = -INFINITY; l_[i] = 0.f;
#pragma unroll
        for (int j = 0; j < 4; ++j) o_[i][j] = 0.f;
    }

    const int ktiles = 2 * qt + 2;
    const int lr = tid >> 3;
    const int lc = (tid & 7) * 4;

    for (int kt = 0; kt < ktiles; ++kt) {
        __syncthreads();
        {
            const float* kb = qkv + (size_t)(b * SEQ + kt * KT + lr) * (3 * D_MODEL)
                            + D_MODEL + h * HEAD_DIM + lc;
            const float* vb = kb + D_MODEL;
            *(float4*)&Ks[lr][lc]      = *(const float4*)(kb);
            *(float4*)&Ks[lr][lc + 32] = *(const float4*)(kb + 32);
            *(float4*)&Vs[lr][lc]      = *(const float4*)(vb);
            *(float4*)&Vs[lr][lc + 32] = *(const float4*)(vb + 32);
        }
        __syncthreads();

        float s0[4], s1[4];
#pragma unroll
        for (int i = 0; i < 4; ++i) { s0[i] = 0.f; s1[i] = 0.f; }
#pragma unroll
        for (int d4 = 0; d4 < 16; ++d4) {
            float4 k0 = *(const float4*)&Ks[tx][d4 * 4];
            float4 k1 = *(const float4*)&Ks[tx + 16][d4 * 4];
#pragma unroll
            for (int i = 0; i < 4; ++i) {
                float4 qv = *(const float4*)&Qs[ty4 + i][d4 * 4];
                s0[i] += qv.x * k0.x + qv.y * k0.y + qv.z * k0.z + qv.w * k0.w;
                s1[i] += qv.x * k1.x + qv.y * k1.y + qv.z * k1.z + qv.w * k1.w;
            }
        }

        const int cg0 = kt * KT + tx;
        const int cg1 = cg0 + 16;
        const int ok0m = am[b * SEQ + cg0];
        const int ok1m = am[b * SEQ + cg1];
#pragma unroll
        for (int i = 0; i < 4; ++i) {
            int rg = qt * QT + ty4 + i;
            if (cg0 > rg || !ok0m) s0[i] = -INFINITY;
            if (cg1 > rg || !ok1m) s1[i] = -INFINITY;
        }

#pragma unroll
        for (int i = 0; i < 4; ++i) {
            float mx = fmaxf(s0[i], s1[i]);
            mx = fmaxf(mx, __shfl_xor(mx, 1, 16));
            mx = fmaxf(mx, __shfl_xor(mx, 2, 16));
            mx = fmaxf(mx, __shfl_xor(mx, 4, 16));
            mx = fmaxf(mx, __shfl_xor(mx, 8, 16));
            float mnew = fmaxf(m_[i], mx);
            float alpha, p0, p1;
            if (mnew == -INFINITY) {
                alpha = 1.f; p0 = 0.f; p1 = 0.f;
            } else {
                alpha = __expf(m_[i] - mnew);
                p0 = __expf(s0[i] - mnew);
                p1 = __expf(s1[i] - mnew);
            }
            float rs = p0 + p1;
            rs += __shfl_xor(rs, 1, 16);
            rs += __shfl_xor(rs, 2, 16);
            rs += __shfl_xor(rs, 4, 16);
            rs += __shfl_xor(rs, 8, 16);
            l_[i] = l_[i] * alpha + rs;
            m_[i] = mnew;
#pragma unroll
            for (int j = 0; j < 4; ++j) o_[i][j] *= alpha;
            Ps[ty4 + i][tx] = p0;
            Ps[ty4 + i][tx + 16] = p1;
        }
        __syncthreads();

#pragma unroll
        for (int k4 = 0; k4 < 8; ++k4) {
            float pr[4][4];
#pragma unroll
            for (int i = 0; i < 4; ++i)
                *(float4*)&pr[i][0] = *(const float4*)&Ps[ty4 + i][k4 * 4];
#pragma unroll
            for (int kk = 0; kk < 4; ++kk) {
                float4 v = *(const float4*)&Vs[k4 * 4 + kk][tx * 4];
#pragma unroll
                for (int i = 0; i < 4; ++i) {
                    o_[i][0] += pr[i][kk] * v.x;
                    o_[i][1] += pr[i][kk] * v.y;
                    o_[i][2] += pr[i][kk] * v.z;
                    o_[i][3] += pr[i][kk] * v.w;
                }
            }
        }
    }

#pragma unroll
    for (int i = 0; i < 4; ++i) {
        float rl = 1.0f / l_[i];
        float4 o;
        o.x = o_[i][0] * rl; o.y = o_[i][1] * rl;
        o.z = o_[i][2] * rl; o.w = o_[i][3] * rl;
        float* dst = attn + (size_t)(b * SEQ + qt * QT + ty4 + i) * D_MODEL
                   + h * HEAD_DIM + tx * 4;
        *(float4*)dst = o;
    }
}

// ---------------------------------------------------------------------------
extern "C" void kernel_launch(void* const* d_in, const int* in_sizes, int n_in,
                              void* d_out, int out_size, void* d_ws, size_t ws_size,
                              hipStream_t stream)
{
    const float* x    = (const float*)d_in[0];
    const int*   am   = (const int*)d_in[1];
    const float* Wqkv = (const float*)d_in[2];
    const float* bqkv = (const float*)d_in[3];
    const float* Wout = (const float*)d_in[4];
    const float* bout = (const float*)d_in[5];
    float* out = (float*)d_out;

    // ws layout (76.3 MB): Bt (12.6 MB, reused for both weights) | qkv | attn
    unsigned short* Bt = (unsigned short*)d_ws;                    // 3072x2048 bf16
    float* qkv  = (float*)((char*)d_ws + 12582912);                // 4096x3072 f32
    float* attn = (float*)((char*)d_ws + 12582912 + 50331648);     // 4096x1024 f32

    // 1) split/transpose W_qkv -> Bt ; qkv = x @ W_qkv + b (bf16x3 MFMA)
    split_w_t<<<dim3(3072 / 32, 1024 / 32), 256, 0, stream>>>(Wqkv, 3072, Bt);
    gemm_x3<128, 128, 2, 2, 4, 4>
        <<<dim3(3072 / 128, TOKENS / 128), 256, 0, stream>>>(
            x, Bt, bqkv, qkv, TOKENS, 3072);

    // 2) RoPE in place
    rope_kernel<<<(TOKENS * N_HEADS * 32) / 256, 256, 0, stream>>>(qkv);

    // 3) flash attention (heavy-first schedule)
    flash_attn_kernel<<<dim3((SEQ / QT) * BATCH * N_HEADS), 256, 0, stream>>>(
        qkv, am, attn);

    // 4) split/transpose W_out -> Bt ; out = attn @ W_out + b (bf16x3 MFMA)
    split_w_t<<<dim3(1024 / 32, 1024 / 32), 256, 0, stream>>>(Wout, 1024, Bt);
    gemm_x3<64, 128, 1, 4, 4, 2>
        <<<dim3(1024 / 128, TOKENS / 64), 256, 0, stream>>>(
            attn, Bt, bout, out, TOKENS, 1024);
}

// Round 3
// 520.185 us; speedup vs baseline: 2.3561x; 1.5318x over previous
//
#include <hip/hip_runtime.h>
#include <math.h>
#include <stdint.h>

#define D_MODEL 1024
#define N_HEADS 16
#define HEAD_DIM 64
#define BATCH 2
#define SEQ 2048
#define TOKENS (BATCH * SEQ)   // 4096

typedef __attribute__((ext_vector_type(8))) short short8;   // 8 bf16 = 4 VGPRs
typedef __attribute__((ext_vector_type(4))) float floatx4;  // MFMA C/D frag

__device__ __forceinline__ unsigned short f2bf(float f) {
    uint32_t u = __float_as_uint(f);
    u += 0x7fffu + ((u >> 16) & 1u);
    return (unsigned short)(u >> 16);
}
__device__ __forceinline__ float bf2f(unsigned short h) {
    return __uint_as_float(((uint32_t)h) << 16);
}

// ---------------------------------------------------------------------------
// Weight transpose + bf16 hi/lo split (unchanged from R2)
// ---------------------------------------------------------------------------
__global__ __launch_bounds__(256) void split_w_t(
    const float* __restrict__ W, int N, unsigned short* __restrict__ Bt)
{
    __shared__ float t[32][33];
    const int tid = threadIdx.x;
    const int n0 = blockIdx.x * 32, k0 = blockIdx.y * 32;
    const int c = tid & 31, r = tid >> 5;
#pragma unroll
    for (int i = 0; i < 4; ++i)
        t[r + 8 * i][c] = W[(size_t)(k0 + r + 8 * i) * N + n0 + c];
    __syncthreads();
#pragma unroll
    for (int i = 0; i < 4; ++i) {
        int dn = r + 8 * i;
        float f = t[c][dn];
        unsigned short hi = f2bf(f);
        unsigned short lo = f2bf(f - bf2f(hi));
        size_t row = (size_t)(n0 + dn) * 2048;
        Bt[row + k0 + c] = hi;
        Bt[row + 1024 + k0 + c] = lo;
    }
}

// ---------------------------------------------------------------------------
// bf16x3 MFMA GEMM (unchanged from R2, passing)
// ---------------------------------------------------------------------------
template<int BM, int BN, int WAVES_M, int WAVES_N, int FM, int FN>
__global__ __launch_bounds__(256) void gemm_x3(
    const float* __restrict__ A, const unsigned short* __restrict__ Bt,
    const float* __restrict__ bias, float* __restrict__ C, int M, int N)
{
    __shared__ __align__(16) short As[BM * 32];
    __shared__ __align__(16) short Bs[BN * 32];

    const int tid = threadIdx.x;
    const int m0 = blockIdx.y * BM, n0 = blockIdx.x * BN;
    const int w = tid >> 6, lane = tid & 63;
    const int l15 = lane & 15, q = lane >> 4;
    const int wm = w / WAVES_N, wn = w % WAVES_N;

    floatx4 acc[FM][FN];
#pragma unroll
    for (int fm = 0; fm < FM; ++fm)
#pragma unroll
        for (int fn = 0; fn < FN; ++fn) acc[fm][fn] = (floatx4)0.f;

    constexpr int NA = BM * 4 / 256;
    constexpr int NB = BN * 4 / 256;

    for (int k0 = 0; k0 < 3072; k0 += 32) {
        const int kk = k0 & 1023;
        const bool islo = (k0 >= 2048);
        const int kB = (k0 < 2048) ? k0 : (k0 - 2048);

        float4 fa[NA][2];
        uint4 vb[NB];
#pragma unroll
        for (int i = 0; i < NA; ++i) {
            int c = tid + i * 256, m = c >> 2, kb = c & 3;
            const float* gp = A + (size_t)(m0 + m) * 1024 + kk + kb * 8;
            fa[i][0] = *(const float4*)gp;
            fa[i][1] = *(const float4*)(gp + 4);
        }
#pragma unroll
        for (int i = 0; i < NB; ++i) {
            int c = tid + i * 256, n = c >> 2, kb = c & 3;
            vb[i] = *(const uint4*)(Bt + (size_t)(n0 + n) * 2048 + kB + kb * 8);
        }
        __syncthreads();
#pragma unroll
        for (int i = 0; i < NA; ++i) {
            int c = tid + i * 256;
            float v[8];
            *(float4*)&v[0] = fa[i][0];
            *(float4*)&v[4] = fa[i][1];
            unsigned short u[8];
#pragma unroll
            for (int j = 0; j < 8; ++j) {
                unsigned short h = f2bf(v[j]);
                u[j] = islo ? f2bf(v[j] - bf2f(h)) : h;
            }
            uint4 wv;
            wv.x = (uint32_t)u[0] | ((uint32_t)u[1] << 16);
            wv.y = (uint32_t)u[2] | ((uint32_t)u[3] << 16);
            wv.z = (uint32_t)u[4] | ((uint32_t)u[5] << 16);
            wv.w = (uint32_t)u[6] | ((uint32_t)u[7] << 16);
            ((uint4*)As)[c] = wv;
        }
#pragma unroll
        for (int i = 0; i < NB; ++i) ((uint4*)Bs)[tid + i * 256] = vb[i];
        __syncthreads();

        short8 af[FM], bfr[FN];
#pragma unroll
        for (int fm = 0; fm < FM; ++fm)
            af[fm] = *(const short8*)(As + (wm * FM * 16 + fm * 16 + l15) * 32 + q * 8);
#pragma unroll
        for (int fn = 0; fn < FN; ++fn)
            bfr[fn] = *(const short8*)(Bs + (wn * FN * 16 + fn * 16 + l15) * 32 + q * 8);
#pragma unroll
        for (int fm = 0; fm < FM; ++fm)
#pragma unroll
            for (int fn = 0; fn < FN; ++fn)
                acc[fm][fn] = __builtin_amdgcn_mfma_f32_16x16x32_bf16(
                    af[fm], bfr[fn], acc[fm][fn], 0, 0, 0);
    }

#pragma unroll
    for (int fm = 0; fm < FM; ++fm)
#pragma unroll
        for (int fn = 0; fn < FN; ++fn) {
            int col = n0 + (wn * FN + fn) * 16 + l15;
            float bv = bias[col];
#pragma unroll
            for (int r = 0; r < 4; ++r) {
                int row = m0 + (wm * FM + fm) * 16 + q * 4 + r;
                C[(size_t)row * N + col] = acc[fm][fn][r] + bv;
            }
        }
}

// ---------------------------------------------------------------------------
// prep_qkv: reads fp32 qkv, applies RoPE to q,k (+1/8 scale to q), splits all
// to bf16 hi/lo in flash-friendly layouts:
//   Qh/Ql, Kh/Kl: [bh][t][64]  (head-separated, d contiguous)
//   Vh/Vl:        [bh][d][2048] (transposed: t contiguous)
// Grid: 1024 blocks = 32 bh x 32 t-tiles of 64. 256 threads.
// ---------------------------------------------------------------------------
__global__ __launch_bounds__(256) void prep_qkv(
    const float* __restrict__ qkv,
    unsigned short* __restrict__ Qh, unsigned short* __restrict__ Ql,
    unsigned short* __restrict__ Kh, unsigned short* __restrict__ Kl,
    unsigned short* __restrict__ Vh, unsigned short* __restrict__ Vl)
{
    __shared__ float vt[64][65];
    const int tid = threadIdx.x;
    const int lin = blockIdx.x;
    const int tt = lin & 31, bh = lin >> 5;
    const int b = bh >> 4, h = bh & 15;
    const int r = tid >> 2;
    const int dblk = (tid & 3) * 16;
    const int tg = tt * 64 + r;                 // position in sequence
    const size_t src = (size_t)(b * SEQ + tg) * 3072 + h * 64 + dblk;
    const size_t dst = ((size_t)bh * SEQ + tg) * 64 + dblk;

    float q[16], k[16], v[16];
#pragma unroll
    for (int i = 0; i < 4; ++i) {
        *(float4*)&q[4 * i] = *(const float4*)(qkv + src + 4 * i);
        *(float4*)&k[4 * i] = *(const float4*)(qkv + src + 1024 + 4 * i);
        *(float4*)&v[4 * i] = *(const float4*)(qkv + src + 2048 + 4 * i);
    }
    // RoPE (identical math to R2's passing rope_kernel)
#pragma unroll
    for (int j = 0; j < 16; j += 2) {
        int pr = (dblk + j) >> 1;
        double e = (double)(2 * pr) / 64.0;
        float inv = (float)exp2(-e * 13.287712379549449); // log2(10000)
        float ang = (float)tg * inv;
        float s, c;
        __sincosf(ang, &s, &c);
        float qe = q[j], qo = q[j + 1];
        q[j] = qe * c - qo * s; q[j + 1] = qe * s + qo * c;
        float ke = k[j], ko = k[j + 1];
        k[j] = ke * c - ko * s; k[j + 1] = ke * s + ko * c;
    }
    uint32_t ph[8], pl[8];
#pragma unroll
    for (int j = 0; j < 8; ++j) {
        float f0 = q[2 * j] * 0.125f, f1 = q[2 * j + 1] * 0.125f;
        unsigned short h0 = f2bf(f0), h1 = f2bf(f1);
        ph[j] = (uint32_t)h0 | ((uint32_t)h1 << 16);
        pl[j] = (uint32_t)f2bf(f0 - bf2f(h0)) | ((uint32_t)f2bf(f1 - bf2f(h1)) << 16);
    }
    *(uint4*)(Qh + dst) = *(uint4*)&ph[0]; *(uint4*)(Qh + dst + 8) = *(uint4*)&ph[4];
    *(uint4*)(Ql + dst) = *(uint4*)&pl[0]; *(uint4*)(Ql + dst + 8) = *(uint4*)&pl[4];
#pragma unroll
    for (int j = 0; j < 8; ++j) {
        float f0 = k[2 * j], f1 = k[2 * j + 1];
        unsigned short h0 = f2bf(f0), h1 = f2bf(f1);
        ph[j] = (uint32_t)h0 | ((uint32_t)h1 << 16);
        pl[j] = (uint32_t)f2bf(f0 - bf2f(h0)) | ((uint32_t)f2bf(f1 - bf2f(h1)) << 16);
    }
    *(uint4*)(Kh + dst) = *(uint4*)&ph[0]; *(uint4*)(Kh + dst + 8) = *(uint4*)&ph[4];
    *(uint4*)(Kl + dst) = *(uint4*)&pl[0]; *(uint4*)(Kl + dst + 8) = *(uint4*)&pl[4];

    // V transpose via LDS
#pragma unroll
    for (int j = 0; j < 16; ++j) vt[r][dblk + j] = v[j];
    __syncthreads();
    const int d2 = tid >> 2;
    const int tb = (tid & 3) * 16;
#pragma unroll
    for (int j = 0; j < 8; ++j) {
        float f0 = vt[tb + 2 * j][d2], f1 = vt[tb + 2 * j + 1][d2];
        unsigned short h0 = f2bf(f0), h1 = f2bf(f1);
        ph[j] = (uint32_t)h0 | ((uint32_t)h1 << 16);
        pl[j] = (uint32_t)f2bf(f0 - bf2f(h0)) | ((uint32_t)f2bf(f1 - bf2f(h1)) << 16);
    }
    const size_t vdst = ((size_t)bh * 64 + d2) * SEQ + tt * 64 + tb;
    *(uint4*)(Vh + vdst) = *(uint4*)&ph[0]; *(uint4*)(Vh + vdst + 8) = *(uint4*)&ph[4];
    *(uint4*)(Vl + vdst) = *(uint4*)&pl[0]; *(uint4*)(Vl + vdst + 8) = *(uint4*)&pl[4];
}

// ---------------------------------------------------------------------------
// MFMA flash attention. QK^T = x3 bf16 (fp32-grade), PV = Ph*(Vh+Vl).
// Block = 256 thr (4 waves), handles q-tile pair {p, 31-p} for one (b,h)
// -> exactly 33 KV-iterations per block (perfect balance), 512 blocks.
// Wave w owns q-rows w*16..w*16+15; KT=64 per iteration.
// LDS rows padded to 72 shorts (uniform 8-phase b128 access).
// ---------------------------------------------------------------------------
#define LDR 72

__global__ __launch_bounds__(256, 2) void flash_mfma(
    const unsigned short* __restrict__ Qh, const unsigned short* __restrict__ Ql,
    const unsigned short* __restrict__ Kh, const unsigned short* __restrict__ Kl,
    const unsigned short* __restrict__ Vh, const unsigned short* __restrict__ Vl,
    const int* __restrict__ am, float* __restrict__ attn)
{
    __shared__ __align__(16) unsigned short sKh[64 * LDR];
    __shared__ __align__(16) unsigned short sKl[64 * LDR];
    __shared__ __align__(16) unsigned short sVh[64 * LDR];
    __shared__ __align__(16) unsigned short sVl[64 * LDR];
    __shared__ __align__(16) unsigned short sP[4 * 16 * LDR];  // per-wave private

    const int tid = threadIdx.x;
    const int lane = tid & 63, w = tid >> 6;
    const int l15 = lane & 15, quad = lane >> 4;
    const int lin = blockIdx.x;
    const int bh = lin & 31;
    const int p = lin >> 5;            // 0..15
    const int b = bh >> 4, h = bh & 15;
    unsigned short* pbase = sP + w * (16 * LDR);

#pragma unroll
    for (int phase = 0; phase < 2; ++phase) {
        const int qt = phase ? (31 - p) : p;

        // Q fragments -> registers (once per phase)
        const size_t qb = ((size_t)bh * SEQ + qt * 64 + w * 16 + l15) * 64 + quad * 8;
        const short8 qh0 = *(const short8*)(Qh + qb);
        const short8 qh1 = *(const short8*)(Qh + qb + 32);
        const short8 ql0 = *(const short8*)(Ql + qb);
        const short8 ql1 = *(const short8*)(Ql + qb + 32);

        floatx4 O[4];
        float m_[4], l_[4];
#pragma unroll
        for (int nf = 0; nf < 4; ++nf) O[nf] = (floatx4)0.f;
#pragma unroll
        for (int r = 0; r < 4; ++r) { m_[r] = -INFINITY; l_[r] = 0.f; }

        const int ktiles = qt + 1;
        for (int kt = 0; kt < ktiles; ++kt) {
            __syncthreads();   // everyone done reading previous K/V tiles
#pragma unroll
            for (int i = 0; i < 2; ++i) {
                const int u = tid + i * 256;
                const int row = u >> 3, blk = u & 7;
                const size_t kg = ((size_t)bh * SEQ + kt * 64 + row) * 64 + blk * 8;
                const size_t vg = ((size_t)bh * 64 + row) * SEQ + kt * 64 + blk * 8;
                const uint4 a0 = *(const uint4*)(Kh + kg);
                const uint4 a1 = *(const uint4*)(Kl + kg);
                const uint4 a2 = *(const uint4*)(Vh + vg);
                const uint4 a3 = *(const uint4*)(Vl + vg);
                const int lo = row * LDR + blk * 8;
                *(uint4*)&sKh[lo] = a0;
                *(uint4*)&sKl[lo] = a1;
                *(uint4*)&sVh[lo] = a2;
                *(uint4*)&sVl[lo] = a3;
            }
            __syncthreads();

            // ---- S = QK^T (x3) ----
            floatx4 S[4];
#pragma unroll
            for (int nf = 0; nf < 4; ++nf) {
                const int kb = (nf * 16 + l15) * LDR + quad * 8;
                const short8 kh0 = *(const short8*)&sKh[kb];
                const short8 kh1 = *(const short8*)&sKh[kb + 32];
                const short8 kl0 = *(const short8*)&sKl[kb];
                const short8 kl1 = *(const short8*)&sKl[kb + 32];
                floatx4 s = (floatx4)0.f;
                s = __builtin_amdgcn_mfma_f32_16x16x32_bf16(qh0, kh0, s, 0, 0, 0);
                s = __builtin_amdgcn_mfma_f32_16x16x32_bf16(qh1, kh1, s, 0, 0, 0);
                s = __builtin_amdgcn_mfma_f32_16x16x32_bf16(qh0, kl0, s, 0, 0, 0);
                s = __builtin_amdgcn_mfma_f32_16x16x32_bf16(qh1, kl1, s, 0, 0, 0);
                s = __builtin_amdgcn_mfma_f32_16x16x32_bf16(ql0, kh0, s, 0, 0, 0);
                s = __builtin_amdgcn_mfma_f32_16x16x32_bf16(ql1, kh1, s, 0, 0, 0);
                S[nf] = s;
            }

            // ---- mask (causal + padding) ----
#pragma unroll
            for (int nf = 0; nf < 4; ++nf) {
                const int colg = kt * 64 + nf * 16 + l15;
                const bool amok = am[b * SEQ + colg] != 0;
#pragma unroll
                for (int r = 0; r < 4; ++r) {
                    const int rowg = qt * 64 + w * 16 + quad * 4 + r;
                    if (!amok || colg > rowg) S[nf][r] = -INFINITY;
                }
            }

            // ---- online softmax + stage Ph (wave-private LDS) ----
            float alpha[4];
#pragma unroll
            for (int r = 0; r < 4; ++r) {
                float mx = fmaxf(fmaxf(S[0][r], S[1][r]), fmaxf(S[2][r], S[3][r]));
                mx = fmaxf(mx, __shfl_xor(mx, 1));
                mx = fmaxf(mx, __shfl_xor(mx, 2));
                mx = fmaxf(mx, __shfl_xor(mx, 4));
                mx = fmaxf(mx, __shfl_xor(mx, 8));
                const float mnew = fmaxf(m_[r], mx);
                float a, pv[4];
                if (mnew == -INFINITY) {
                    a = 1.f; pv[0] = pv[1] = pv[2] = pv[3] = 0.f;
                } else {
                    a = __expf(m_[r] - mnew);
#pragma unroll
                    for (int nf = 0; nf < 4; ++nf) pv[nf] = __expf(S[nf][r] - mnew);
                }
                float rs = pv[0] + pv[1] + pv[2] + pv[3];
                rs += __shfl_xor(rs, 1);
                rs += __shfl_xor(rs, 2);
                rs += __shfl_xor(rs, 4);
                rs += __shfl_xor(rs, 8);
                l_[r] = l_[r] * a + rs;
                m_[r] = mnew;
                alpha[r] = a;
#pragma unroll
                for (int nf = 0; nf < 4; ++nf)
                    pbase[(quad * 4 + r) * LDR + nf * 16 + l15] = f2bf(pv[nf]);
            }
#pragma unroll
            for (int nf = 0; nf < 4; ++nf)
#pragma unroll
                for (int r = 0; r < 4; ++r) O[nf][r] *= alpha[r];

            // ---- O += Ph @ (Vh + Vl)  (same-wave LDS RAW: lgkmcnt only) ----
            const short8 pf0 = *(const short8*)(pbase + l15 * LDR + quad * 8);
            const short8 pf1 = *(const short8*)(pbase + l15 * LDR + 32 + quad * 8);
#pragma unroll
            for (int nf = 0; nf < 4; ++nf) {
                const int vb = (nf * 16 + l15) * LDR + quad * 8;
                const short8 vh0 = *(const short8*)&sVh[vb];
                const short8 vh1 = *(const short8*)&sVh[vb + 32];
                const short8 vl0 = *(const short8*)&sVl[vb];
                const short8 vl1 = *(const short8*)&sVl[vb + 32];
                floatx4 o = O[nf];
                o = __builtin_amdgcn_mfma_f32_16x16x32_bf16(pf0, vh0, o, 0, 0, 0);
                o = __builtin_amdgcn_mfma_f32_16x16x32_bf16(pf1, vh1, o, 0, 0, 0);
                o = __builtin_amdgcn_mfma_f32_16x16x32_bf16(pf0, vl0, o, 0, 0, 0);
                o = __builtin_amdgcn_mfma_f32_16x16x32_bf16(pf1, vl1, o, 0, 0, 0);
                O[nf] = o;
            }
        }

        // ---- finalize: divide by l, store ----
        float rl[4];
#pragma unroll
        for (int r = 0; r < 4; ++r) rl[r] = 1.0f / l_[r];
#pragma unroll
        for (int nf = 0; nf < 4; ++nf)
#pragma unroll
            for (int r = 0; r < 4; ++r) {
                const int tok = b * SEQ + qt * 64 + w * 16 + quad * 4 + r;
                attn[(size_t)tok * D_MODEL + h * 64 + nf * 16 + l15] = O[nf][r] * rl[r];
            }
    }
}

// ---------------------------------------------------------------------------
extern "C" void kernel_launch(void* const* d_in, const int* in_sizes, int n_in,
                              void* d_out, int out_size, void* d_ws, size_t ws_size,
                              hipStream_t stream)
{
    const float* x    = (const float*)d_in[0];
    const int*   am   = (const int*)d_in[1];
    const float* Wqkv = (const float*)d_in[2];
    const float* bqkv = (const float*)d_in[3];
    const float* Wout = (const float*)d_in[4];
    const float* bout = (const float*)d_in[5];
    float* out = (float*)d_out;

    // ws layout (113.2 MB):
    //   Bt 12.6MB | qkv 50.3MB (first 16.8MB reused as attn after prep) |
    //   Qh Ql Kh Kl Vh Vl (8.39MB each)
    char* ws = (char*)d_ws;
    unsigned short* Bt = (unsigned short*)ws;
    float* qkv  = (float*)(ws + 12582912);
    float* attn = qkv;                                  // alias: qkv dead after prep
    unsigned short* Qh = (unsigned short*)(ws + 62914560);
    unsigned short* Ql = Qh + 4194304;
    unsigned short* Kh = Ql + 4194304;
    unsigned short* Kl = Kh + 4194304;
    unsigned short* Vh = Kl + 4194304;
    unsigned short* Vl = Vh + 4194304;

    // 1) qkv = x @ W_qkv + b
    split_w_t<<<dim3(96, 32), 256, 0, stream>>>(Wqkv, 3072, Bt);
    gemm_x3<128, 128, 2, 2, 4, 4><<<dim3(24, 32), 256, 0, stream>>>(
        x, Bt, bqkv, qkv, TOKENS, 3072);

    // 2) RoPE + scale + bf16 hi/lo split + V transpose
    prep_qkv<<<1024, 256, 0, stream>>>(qkv, Qh, Ql, Kh, Kl, Vh, Vl);

    // 3) MFMA flash attention (paired q-tiles: perfectly balanced)
    flash_mfma<<<512, 256, 0, stream>>>(Qh, Ql, Kh, Kl, Vh, Vl, am, attn);

    // 4) out = attn @ W_out + b
    split_w_t<<<dim3(32, 32), 256, 0, stream>>>(Wout, 1024, Bt);
    gemm_x3<64, 128, 1, 4, 4, 2><<<dim3(8, 64), 256, 0, stream>>>(
        attn, Bt, bout, out, TOKENS, 1024);
}

// Round 4
// 381.467 us; speedup vs baseline: 3.2128x; 1.3636x over previous
//
#include <hip/hip_runtime.h>
#include <math.h>
#include <stdint.h>

#define D_MODEL 1024
#define N_HEADS 16
#define HEAD_DIM 64
#define BATCH 2
#define SEQ 2048
#define TOKENS (BATCH * SEQ)   // 4096

typedef __attribute__((ext_vector_type(8))) short short8;   // 8 bf16 = 4 VGPRs
typedef __attribute__((ext_vector_type(4))) float floatx4;  // MFMA C/D frag

__device__ __forceinline__ unsigned short f2bf(float f) {
    uint32_t u = __float_as_uint(f);
    u += 0x7fffu + ((u >> 16) & 1u);
    return (unsigned short)(u >> 16);
}
__device__ __forceinline__ float bf2f(unsigned short h) {
    return __uint_as_float(((uint32_t)h) << 16);
}

// async global -> LDS, 16B per lane; LDS dest = wave-uniform base + lane*16
#define GLD_LDS16(gp, lp) __builtin_amdgcn_global_load_lds(                 \
    (const __attribute__((address_space(1))) void*)(gp),                    \
    (__attribute__((address_space(3))) void*)(lp), 16, 0, 0)

// ---------------------------------------------------------------------------
// split_a: X fp32 [rows][1024] -> Ax bf16 [rows][2048] (hi | lo along k)
// ---------------------------------------------------------------------------
__global__ __launch_bounds__(256) void split_a(
    const float* __restrict__ X, unsigned short* __restrict__ Ax)
{
    const int idx = blockIdx.x * 256 + threadIdx.x;
    const int row = idx >> 8;            // 256 threads cover one 1024-row
    const int c = (idx & 255) * 4;
    float4 v = *(const float4*)(X + (size_t)row * 1024 + c);
    float f[4] = {v.x, v.y, v.z, v.w};
    uint32_t hp[2], lp[2];
#pragma unroll
    for (int j = 0; j < 2; ++j) {
        unsigned short h0 = f2bf(f[2 * j]), h1 = f2bf(f[2 * j + 1]);
        hp[j] = (uint32_t)h0 | ((uint32_t)h1 << 16);
        lp[j] = (uint32_t)f2bf(f[2 * j] - bf2f(h0)) |
                ((uint32_t)f2bf(f[2 * j + 1] - bf2f(h1)) << 16);
    }
    *(uint2*)(Ax + (size_t)row * 2048 + c) = make_uint2(hp[0], hp[1]);
    *(uint2*)(Ax + (size_t)row * 2048 + 1024 + c) = make_uint2(lp[0], lp[1]);
}

// ---------------------------------------------------------------------------
// Weight transpose + bf16 hi/lo split (unchanged, passing)
// ---------------------------------------------------------------------------
__global__ __launch_bounds__(256) void split_w_t(
    const float* __restrict__ W, int N, unsigned short* __restrict__ Bt)
{
    __shared__ float t[32][33];
    const int tid = threadIdx.x;
    const int n0 = blockIdx.x * 32, k0 = blockIdx.y * 32;
    const int c = tid & 31, r = tid >> 5;
#pragma unroll
    for (int i = 0; i < 4; ++i)
        t[r + 8 * i][c] = W[(size_t)(k0 + r + 8 * i) * N + n0 + c];
    __syncthreads();
#pragma unroll
    for (int i = 0; i < 4; ++i) {
        int dn = r + 8 * i;
        float f = t[c][dn];
        unsigned short hi = f2bf(f);
        unsigned short lo = f2bf(f - bf2f(hi));
        size_t row = (size_t)(n0 + dn) * 2048;
        Bt[row + k0 + c] = hi;
        Bt[row + 1024 + k0 + c] = lo;
    }
}

// ---------------------------------------------------------------------------
// Pure-bf16 MFMA GEMM with x3 hi/lo accumulation (m97 structure):
//   C[M,N] = A[M,1024]fp32-equiv @ W[1024,N] + bias
// A pre-split: Ax [M][2048] = hi|lo ; B pre-split: Bt [N][2048] = hi|lo.
// Segments: (Ah,Bh), (Ah,Bl), (Al,Bh). BK=32, global_load_lds width-16
// staging (LDS layout = DMA lane order, row-major [row][32], no padding).
// 256 threads = WM x WN waves, each computing (FM x FN) 16x16 frags.
// ---------------------------------------------------------------------------
template<int WM, int WN, int FM, int FN>
__global__ __launch_bounds__(256) void gemm_mfma_x3(
    const unsigned short* __restrict__ Ax, const unsigned short* __restrict__ Bt,
    const float* __restrict__ bias, float* __restrict__ C, int M, int N)
{
    constexpr int BM = WM * FM * 16;
    constexpr int BN = WN * FN * 16;
    constexpr int NA = BM / 64;          // global_load_lds instrs per wave (A)
    constexpr int NB = BN / 64;

    __shared__ __align__(16) unsigned short As[BM * 32];
    __shared__ __align__(16) unsigned short Bs[BN * 32];

    const int tid = threadIdx.x;
    const int w = tid >> 6, lane = tid & 63;
    const int l15 = lane & 15, quad = lane >> 4;
    const int wm = w / WN, wn = w % WN;
    const int m0 = blockIdx.y * BM, n0 = blockIdx.x * BN;

    // per-lane global base pointers (k=0 of hi section)
    const unsigned short* aG[NA];
    const unsigned short* bG[NB];
#pragma unroll
    for (int i = 0; i < NA; ++i)
        aG[i] = Ax + (size_t)(m0 + (w * NA + i) * 16 + (lane >> 2)) * 2048
                   + (lane & 3) * 8;
#pragma unroll
    for (int i = 0; i < NB; ++i)
        bG[i] = Bt + (size_t)(n0 + (w * NB + i) * 16 + (lane >> 2)) * 2048
                   + (lane & 3) * 8;

    floatx4 acc[FM][FN];
#pragma unroll
    for (int fm = 0; fm < FM; ++fm)
#pragma unroll
        for (int fn = 0; fn < FN; ++fn) acc[fm][fn] = (floatx4)0.f;

    for (int seg = 0; seg < 3; ++seg) {
        const int ka = (seg == 2) ? 1024 : 0;
        const int kb = (seg == 1) ? 1024 : 0;
        for (int ks = 0; ks < 32; ++ks) {
            const int koA = ka + ks * 32;
            const int koB = kb + ks * 32;
            __syncthreads();             // previous iteration's frag reads done
#pragma unroll
            for (int i = 0; i < NA; ++i)
                GLD_LDS16(aG[i] + koA, As + (w * NA + i) * 512);
#pragma unroll
            for (int i = 0; i < NB; ++i)
                GLD_LDS16(bG[i] + koB, Bs + (w * NB + i) * 512);
            __syncthreads();             // staging (vmcnt) drained

            short8 af[FM], bf[FN];
#pragma unroll
            for (int fm = 0; fm < FM; ++fm)
                af[fm] = *(const short8*)&As[((wm * FM + fm) * 16 + l15) * 32 + quad * 8];
#pragma unroll
            for (int fn = 0; fn < FN; ++fn)
                bf[fn] = *(const short8*)&Bs[((wn * FN + fn) * 16 + l15) * 32 + quad * 8];
#pragma unroll
            for (int fm = 0; fm < FM; ++fm)
#pragma unroll
                for (int fn = 0; fn < FN; ++fn)
                    acc[fm][fn] = __builtin_amdgcn_mfma_f32_16x16x32_bf16(
                        af[fm], bf[fn], acc[fm][fn], 0, 0, 0);
        }
    }

    // epilogue: C/D layout col = lane&15, row = (lane>>4)*4 + reg
#pragma unroll
    for (int fm = 0; fm < FM; ++fm)
#pragma unroll
        for (int fn = 0; fn < FN; ++fn) {
            int col = n0 + (wn * FN + fn) * 16 + l15;
            float bv = bias[col];
#pragma unroll
            for (int r = 0; r < 4; ++r) {
                int row = m0 + (wm * FM + fm) * 16 + quad * 4 + r;
                C[(size_t)row * N + col] = acc[fm][fn][r] + bv;
            }
        }
}

// ---------------------------------------------------------------------------
// prep_qkv (unchanged, passing): RoPE + 1/8 q-scale + bf16 hi/lo split,
// Q/K: [bh][t][64], V: [bh][d][2048] transposed.
// ---------------------------------------------------------------------------
__global__ __launch_bounds__(256) void prep_qkv(
    const float* __restrict__ qkv,
    unsigned short* __restrict__ Qh, unsigned short* __restrict__ Ql,
    unsigned short* __restrict__ Kh, unsigned short* __restrict__ Kl,
    unsigned short* __restrict__ Vh, unsigned short* __restrict__ Vl)
{
    __shared__ float vt[64][65];
    const int tid = threadIdx.x;
    const int lin = blockIdx.x;
    const int tt = lin & 31, bh = lin >> 5;
    const int b = bh >> 4, h = bh & 15;
    const int r = tid >> 2;
    const int dblk = (tid & 3) * 16;
    const int tg = tt * 64 + r;
    const size_t src = (size_t)(b * SEQ + tg) * 3072 + h * 64 + dblk;
    const size_t dst = ((size_t)bh * SEQ + tg) * 64 + dblk;

    float q[16], k[16], v[16];
#pragma unroll
    for (int i = 0; i < 4; ++i) {
        *(float4*)&q[4 * i] = *(const float4*)(qkv + src + 4 * i);
        *(float4*)&k[4 * i] = *(const float4*)(qkv + src + 1024 + 4 * i);
        *(float4*)&v[4 * i] = *(const float4*)(qkv + src + 2048 + 4 * i);
    }
#pragma unroll
    for (int j = 0; j < 16; j += 2) {
        int pr = (dblk + j) >> 1;
        double e = (double)(2 * pr) / 64.0;
        float inv = (float)exp2(-e * 13.287712379549449);
        float ang = (float)tg * inv;
        float s, c;
        __sincosf(ang, &s, &c);
        float qe = q[j], qo = q[j + 1];
        q[j] = qe * c - qo * s; q[j + 1] = qe * s + qo * c;
        float ke = k[j], ko = k[j + 1];
        k[j] = ke * c - ko * s; k[j + 1] = ke * s + ko * c;
    }
    uint32_t ph[8], pl[8];
#pragma unroll
    for (int j = 0; j < 8; ++j) {
        float f0 = q[2 * j] * 0.125f, f1 = q[2 * j + 1] * 0.125f;
        unsigned short h0 = f2bf(f0), h1 = f2bf(f1);
        ph[j] = (uint32_t)h0 | ((uint32_t)h1 << 16);
        pl[j] = (uint32_t)f2bf(f0 - bf2f(h0)) | ((uint32_t)f2bf(f1 - bf2f(h1)) << 16);
    }
    *(uint4*)(Qh + dst) = *(uint4*)&ph[0]; *(uint4*)(Qh + dst + 8) = *(uint4*)&ph[4];
    *(uint4*)(Ql + dst) = *(uint4*)&pl[0]; *(uint4*)(Ql + dst + 8) = *(uint4*)&pl[4];
#pragma unroll
    for (int j = 0; j < 8; ++j) {
        float f0 = k[2 * j], f1 = k[2 * j + 1];
        unsigned short h0 = f2bf(f0), h1 = f2bf(f1);
        ph[j] = (uint32_t)h0 | ((uint32_t)h1 << 16);
        pl[j] = (uint32_t)f2bf(f0 - bf2f(h0)) | ((uint32_t)f2bf(f1 - bf2f(h1)) << 16);
    }
    *(uint4*)(Kh + dst) = *(uint4*)&ph[0]; *(uint4*)(Kh + dst + 8) = *(uint4*)&ph[4];
    *(uint4*)(Kl + dst) = *(uint4*)&pl[0]; *(uint4*)(Kl + dst + 8) = *(uint4*)&pl[4];

#pragma unroll
    for (int j = 0; j < 16; ++j) vt[r][dblk + j] = v[j];
    __syncthreads();
    const int d2 = tid >> 2;
    const int tb = (tid & 3) * 16;
#pragma unroll
    for (int j = 0; j < 8; ++j) {
        float f0 = vt[tb + 2 * j][d2], f1 = vt[tb + 2 * j + 1][d2];
        unsigned short h0 = f2bf(f0), h1 = f2bf(f1);
        ph[j] = (uint32_t)h0 | ((uint32_t)h1 << 16);
        pl[j] = (uint32_t)f2bf(f0 - bf2f(h0)) | ((uint32_t)f2bf(f1 - bf2f(h1)) << 16);
    }
    const size_t vdst = ((size_t)bh * 64 + d2) * SEQ + tt * 64 + tb;
    *(uint4*)(Vh + vdst) = *(uint4*)&ph[0]; *(uint4*)(Vh + vdst + 8) = *(uint4*)&ph[4];
    *(uint4*)(Vl + vdst) = *(uint4*)&pl[0]; *(uint4*)(Vl + vdst + 8) = *(uint4*)&pl[4];
}

// ---------------------------------------------------------------------------
// MFMA flash attention (R3 structure, passing). Only change: epilogue emits
// attn directly as bf16 hi|lo [tok][2048] for the MFMA out-projection.
// ---------------------------------------------------------------------------
#define LDR 72

__global__ __launch_bounds__(256, 2) void flash_mfma(
    const unsigned short* __restrict__ Qh, const unsigned short* __restrict__ Ql,
    const unsigned short* __restrict__ Kh, const unsigned short* __restrict__ Kl,
    const unsigned short* __restrict__ Vh, const unsigned short* __restrict__ Vl,
    const int* __restrict__ am, unsigned short* __restrict__ attnx)
{
    __shared__ __align__(16) unsigned short sKh[64 * LDR];
    __shared__ __align__(16) unsigned short sKl[64 * LDR];
    __shared__ __align__(16) unsigned short sVh[64 * LDR];
    __shared__ __align__(16) unsigned short sVl[64 * LDR];
    __shared__ __align__(16) unsigned short sP[4 * 16 * LDR];

    const int tid = threadIdx.x;
    const int lane = tid & 63, w = tid >> 6;
    const int l15 = lane & 15, quad = lane >> 4;
    const int lin = blockIdx.x;
    const int bh = lin & 31;
    const int p = lin >> 5;
    const int b = bh >> 4, h = bh & 15;
    unsigned short* pbase = sP + w * (16 * LDR);

#pragma unroll
    for (int phase = 0; phase < 2; ++phase) {
        const int qt = phase ? (31 - p) : p;

        const size_t qb = ((size_t)bh * SEQ + qt * 64 + w * 16 + l15) * 64 + quad * 8;
        const short8 qh0 = *(const short8*)(Qh + qb);
        const short8 qh1 = *(const short8*)(Qh + qb + 32);
        const short8 ql0 = *(const short8*)(Ql + qb);
        const short8 ql1 = *(const short8*)(Ql + qb + 32);

        floatx4 O[4];
        float m_[4], l_[4];
#pragma unroll
        for (int nf = 0; nf < 4; ++nf) O[nf] = (floatx4)0.f;
#pragma unroll
        for (int r = 0; r < 4; ++r) { m_[r] = -INFINITY; l_[r] = 0.f; }

        const int ktiles = qt + 1;
        for (int kt = 0; kt < ktiles; ++kt) {
            __syncthreads();
#pragma unroll
            for (int i = 0; i < 2; ++i) {
                const int u = tid + i * 256;
                const int row = u >> 3, blk = u & 7;
                const size_t kg = ((size_t)bh * SEQ + kt * 64 + row) * 64 + blk * 8;
                const size_t vg = ((size_t)bh * 64 + row) * SEQ + kt * 64 + blk * 8;
                const uint4 a0 = *(const uint4*)(Kh + kg);
                const uint4 a1 = *(const uint4*)(Kl + kg);
                const uint4 a2 = *(const uint4*)(Vh + vg);
                const uint4 a3 = *(const uint4*)(Vl + vg);
                const int lo = row * LDR + blk * 8;
                *(uint4*)&sKh[lo] = a0;
                *(uint4*)&sKl[lo] = a1;
                *(uint4*)&sVh[lo] = a2;
                *(uint4*)&sVl[lo] = a3;
            }
            __syncthreads();

            floatx4 S[4];
#pragma unroll
            for (int nf = 0; nf < 4; ++nf) {
                const int kb = (nf * 16 + l15) * LDR + quad * 8;
                const short8 kh0 = *(const short8*)&sKh[kb];
                const short8 kh1 = *(const short8*)&sKh[kb + 32];
                const short8 kl0 = *(const short8*)&sKl[kb];
                const short8 kl1 = *(const short8*)&sKl[kb + 32];
                floatx4 s = (floatx4)0.f;
                s = __builtin_amdgcn_mfma_f32_16x16x32_bf16(qh0, kh0, s, 0, 0, 0);
                s = __builtin_amdgcn_mfma_f32_16x16x32_bf16(qh1, kh1, s, 0, 0, 0);
                s = __builtin_amdgcn_mfma_f32_16x16x32_bf16(qh0, kl0, s, 0, 0, 0);
                s = __builtin_amdgcn_mfma_f32_16x16x32_bf16(qh1, kl1, s, 0, 0, 0);
                s = __builtin_amdgcn_mfma_f32_16x16x32_bf16(ql0, kh0, s, 0, 0, 0);
                s = __builtin_amdgcn_mfma_f32_16x16x32_bf16(ql1, kh1, s, 0, 0, 0);
                S[nf] = s;
            }

#pragma unroll
            for (int nf = 0; nf < 4; ++nf) {
                const int colg = kt * 64 + nf * 16 + l15;
                const bool amok = am[b * SEQ + colg] != 0;
#pragma unroll
                for (int r = 0; r < 4; ++r) {
                    const int rowg = qt * 64 + w * 16 + quad * 4 + r;
                    if (!amok || colg > rowg) S[nf][r] = -INFINITY;
                }
            }

            float alpha[4];
#pragma unroll
            for (int r = 0; r < 4; ++r) {
                float mx = fmaxf(fmaxf(S[0][r], S[1][r]), fmaxf(S[2][r], S[3][r]));
                mx = fmaxf(mx, __shfl_xor(mx, 1));
                mx = fmaxf(mx, __shfl_xor(mx, 2));
                mx = fmaxf(mx, __shfl_xor(mx, 4));
                mx = fmaxf(mx, __shfl_xor(mx, 8));
                const float mnew = fmaxf(m_[r], mx);
                float a, pv[4];
                if (mnew == -INFINITY) {
                    a = 1.f; pv[0] = pv[1] = pv[2] = pv[3] = 0.f;
                } else {
                    a = __expf(m_[r] - mnew);
#pragma unroll
                    for (int nf = 0; nf < 4; ++nf) pv[nf] = __expf(S[nf][r] - mnew);
                }
                float rs = pv[0] + pv[1] + pv[2] + pv[3];
                rs += __shfl_xor(rs, 1);
                rs += __shfl_xor(rs, 2);
                rs += __shfl_xor(rs, 4);
                rs += __shfl_xor(rs, 8);
                l_[r] = l_[r] * a + rs;
                m_[r] = mnew;
                alpha[r] = a;
#pragma unroll
                for (int nf = 0; nf < 4; ++nf)
                    pbase[(quad * 4 + r) * LDR + nf * 16 + l15] = f2bf(pv[nf]);
            }
#pragma unroll
            for (int nf = 0; nf < 4; ++nf)
#pragma unroll
                for (int r = 0; r < 4; ++r) O[nf][r] *= alpha[r];

            const short8 pf0 = *(const short8*)(pbase + l15 * LDR + quad * 8);
            const short8 pf1 = *(const short8*)(pbase + l15 * LDR + 32 + quad * 8);
#pragma unroll
            for (int nf = 0; nf < 4; ++nf) {
                const int vb = (nf * 16 + l15) * LDR + quad * 8;
                const short8 vh0 = *(const short8*)&sVh[vb];
                const short8 vh1 = *(const short8*)&sVh[vb + 32];
                const short8 vl0 = *(const short8*)&sVl[vb];
                const short8 vl1 = *(const short8*)&sVl[vb + 32];
                floatx4 o = O[nf];
                o = __builtin_amdgcn_mfma_f32_16x16x32_bf16(pf0, vh0, o, 0, 0, 0);
                o = __builtin_amdgcn_mfma_f32_16x16x32_bf16(pf1, vh1, o, 0, 0, 0);
                o = __builtin_amdgcn_mfma_f32_16x16x32_bf16(pf0, vl0, o, 0, 0, 0);
                o = __builtin_amdgcn_mfma_f32_16x16x32_bf16(pf1, vl1, o, 0, 0, 0);
                O[nf] = o;
            }
        }

        float rl[4];
#pragma unroll
        for (int r = 0; r < 4; ++r) rl[r] = 1.0f / l_[r];
#pragma unroll
        for (int nf = 0; nf < 4; ++nf)
#pragma unroll
            for (int r = 0; r < 4; ++r) {
                const int tok = b * SEQ + qt * 64 + w * 16 + quad * 4 + r;
                const int col = h * 64 + nf * 16 + l15;
                const float val = O[nf][r] * rl[r];
                const unsigned short hi = f2bf(val);
                const unsigned short lo = f2bf(val - bf2f(hi));
                attnx[(size_t)tok * 2048 + col] = hi;
                attnx[(size_t)tok * 2048 + 1024 + col] = lo;
            }
    }
}

// ---------------------------------------------------------------------------
extern "C" void kernel_launch(void* const* d_in, const int* in_sizes, int n_in,
                              void* d_out, int out_size, void* d_ws, size_t ws_size,
                              hipStream_t stream)
{
    const float* x    = (const float*)d_in[0];
    const int*   am   = (const int*)d_in[1];
    const float* Wqkv = (const float*)d_in[2];
    const float* bqkv = (const float*)d_in[3];
    const float* Wout = (const float*)d_in[4];
    const float* bout = (const float*)d_in[5];
    float* out = (float*)d_out;

    // ws layout (113.2 MB, same footprint as R3):
    //   Bt 12.58MB | qkv fp32 50.33MB (reused as attnx bf16 after prep) |
    //   Qh Ql Kh Kl Vh Vl 8.39MB each (Vh+Vl doubles as Ax before prep)
    char* ws = (char*)d_ws;
    unsigned short* Bt = (unsigned short*)ws;
    float* qkv = (float*)(ws + 12582912);
    unsigned short* attnx = (unsigned short*)qkv;        // alias: qkv dead after prep
    unsigned short* Qh = (unsigned short*)(ws + 62914560);
    unsigned short* Ql = Qh + 4194304;
    unsigned short* Kh = Ql + 4194304;
    unsigned short* Kl = Kh + 4194304;
    unsigned short* Vh = Kl + 4194304;
    unsigned short* Vl = Vh + 4194304;
    unsigned short* Ax = Vh;                             // alias: dead after gemm1

    // 0) split x -> bf16 hi|lo
    split_a<<<4096, 256, 0, stream>>>(x, Ax);

    // 1) qkv = x @ W_qkv + b   (pure-bf16 MFMA, global_load_lds staging)
    split_w_t<<<dim3(96, 32), 256, 0, stream>>>(Wqkv, 3072, Bt);
    gemm_mfma_x3<2, 2, 4, 4><<<dim3(24, 32), 256, 0, stream>>>(
        Ax, Bt, bqkv, qkv, TOKENS, 3072);

    // 2) RoPE + scale + split + V transpose (overwrites Ax region - ordered)
    prep_qkv<<<1024, 256, 0, stream>>>(qkv, Qh, Ql, Kh, Kl, Vh, Vl);

    // 3) MFMA flash attention -> attnx (bf16 hi|lo, into dead qkv region)
    flash_mfma<<<512, 256, 0, stream>>>(Qh, Ql, Kh, Kl, Vh, Vl, am, attnx);

    // 4) out = attn @ W_out + b
    split_w_t<<<dim3(32, 32), 256, 0, stream>>>(Wout, 1024, Bt);
    gemm_mfma_x3<2, 2, 2, 4><<<dim3(8, 64), 256, 0, stream>>>(
        attnx, Bt, bout, out, TOKENS, 1024);
}

// Round 5
// 379.063 us; speedup vs baseline: 3.2332x; 1.0063x over previous
//
#include <hip/hip_runtime.h>
#include <math.h>
#include <stdint.h>

#define D_MODEL 1024
#define N_HEADS 16
#define HEAD_DIM 64
#define BATCH 2
#define SEQ 2048
#define TOKENS (BATCH * SEQ)   // 4096

typedef __attribute__((ext_vector_type(8))) short short8;   // 8 bf16 = 4 VGPRs
typedef __attribute__((ext_vector_type(4))) float floatx4;  // MFMA C/D frag

__device__ __forceinline__ unsigned short f2bf(float f) {
    uint32_t u = __float_as_uint(f);
    u += 0x7fffu + ((u >> 16) & 1u);
    return (unsigned short)(u >> 16);
}
__device__ __forceinline__ float bf2f(unsigned short h) {
    return __uint_as_float(((uint32_t)h) << 16);
}

// async global -> LDS, 16B per lane; LDS dest = wave-uniform base + lane*16
#define GLD_LDS16(gp, lp) __builtin_amdgcn_global_load_lds(                 \
    (const __attribute__((address_space(1))) void*)(gp),                    \
    (__attribute__((address_space(3))) void*)(lp), 16, 0, 0)

// ---------------------------------------------------------------------------
// split_a: X fp32 [rows][1024] -> Ax bf16 [rows][2048] (hi | lo along k)
// ---------------------------------------------------------------------------
__global__ __launch_bounds__(256) void split_a(
    const float* __restrict__ X, unsigned short* __restrict__ Ax)
{
    const int idx = blockIdx.x * 256 + threadIdx.x;
    const int row = idx >> 8;            // 256 threads cover one 1024-row
    const int c = (idx & 255) * 4;
    float4 v = *(const float4*)(X + (size_t)row * 1024 + c);
    float f[4] = {v.x, v.y, v.z, v.w};
    uint32_t hp[2], lp[2];
#pragma unroll
    for (int j = 0; j < 2; ++j) {
        unsigned short h0 = f2bf(f[2 * j]), h1 = f2bf(f[2 * j + 1]);
        hp[j] = (uint32_t)h0 | ((uint32_t)h1 << 16);
        lp[j] = (uint32_t)f2bf(f[2 * j] - bf2f(h0)) |
                ((uint32_t)f2bf(f[2 * j + 1] - bf2f(h1)) << 16);
    }
    *(uint2*)(Ax + (size_t)row * 2048 + c) = make_uint2(hp[0], hp[1]);
    *(uint2*)(Ax + (size_t)row * 2048 + 1024 + c) = make_uint2(lp[0], lp[1]);
}

// ---------------------------------------------------------------------------
// Weight transpose + bf16 hi/lo split (unchanged, passing)
// ---------------------------------------------------------------------------
__global__ __launch_bounds__(256) void split_w_t(
    const float* __restrict__ W, int N, unsigned short* __restrict__ Bt)
{
    __shared__ float t[32][33];
    const int tid = threadIdx.x;
    const int n0 = blockIdx.x * 32, k0 = blockIdx.y * 32;
    const int c = tid & 31, r = tid >> 5;
#pragma unroll
    for (int i = 0; i < 4; ++i)
        t[r + 8 * i][c] = W[(size_t)(k0 + r + 8 * i) * N + n0 + c];
    __syncthreads();
#pragma unroll
    for (int i = 0; i < 4; ++i) {
        int dn = r + 8 * i;
        float f = t[c][dn];
        unsigned short hi = f2bf(f);
        unsigned short lo = f2bf(f - bf2f(hi));
        size_t row = (size_t)(n0 + dn) * 2048;
        Bt[row + k0 + c] = hi;
        Bt[row + 1024 + k0 + c] = lo;
    }
}

// ---------------------------------------------------------------------------
// Pure-bf16 MFMA GEMM with x3 hi/lo accumulation (m97 structure) + LDS
// bank-conflict-free SWIZZLE:
//   staging lane L fetches row L>>2, k-chunk (L&3)^((L>>3)&3) of its window;
//   fragment (l15,quad) reads slot 4*l15 + (quad^((l15>>1)&3)).
//   => every bank-group serves exactly 2 lanes (free; was 8-way).
// ---------------------------------------------------------------------------
template<int WM, int WN, int FM, int FN>
__global__ __launch_bounds__(256) void gemm_mfma_x3(
    const unsigned short* __restrict__ Ax, const unsigned short* __restrict__ Bt,
    const float* __restrict__ bias, float* __restrict__ C, int M, int N)
{
    constexpr int BM = WM * FM * 16;
    constexpr int BN = WN * FN * 16;
    constexpr int NA = BM / 64;          // global_load_lds instrs per wave (A)
    constexpr int NB = BN / 64;

    __shared__ __align__(16) unsigned short As[BM * 32];
    __shared__ __align__(16) unsigned short Bs[BN * 32];

    const int tid = threadIdx.x;
    const int w = tid >> 6, lane = tid & 63;
    const int l15 = lane & 15, quad = lane >> 4;
    const int wm = w / WN, wn = w % WN;
    const int m0 = blockIdx.y * BM, n0 = blockIdx.x * BN;

    // swizzled staging chunk for this lane (see header comment)
    const int ch = (lane & 3) ^ ((lane >> 3) & 3);
    // swizzled fragment-read sub-offset (shorts)
    const int sw = (quad ^ ((l15 >> 1) & 3)) * 8;

    // per-lane global base pointers (k=0 of hi section)
    const unsigned short* aG[NA];
    const unsigned short* bG[NB];
#pragma unroll
    for (int i = 0; i < NA; ++i)
        aG[i] = Ax + (size_t)(m0 + (w * NA + i) * 16 + (lane >> 2)) * 2048
                   + ch * 8;
#pragma unroll
    for (int i = 0; i < NB; ++i)
        bG[i] = Bt + (size_t)(n0 + (w * NB + i) * 16 + (lane >> 2)) * 2048
                   + ch * 8;

    floatx4 acc[FM][FN];
#pragma unroll
    for (int fm = 0; fm < FM; ++fm)
#pragma unroll
        for (int fn = 0; fn < FN; ++fn) acc[fm][fn] = (floatx4)0.f;

    for (int seg = 0; seg < 3; ++seg) {
        const int ka = (seg == 2) ? 1024 : 0;
        const int kb = (seg == 1) ? 1024 : 0;
        for (int ks = 0; ks < 32; ++ks) {
            const int koA = ka + ks * 32;
            const int koB = kb + ks * 32;
            __syncthreads();             // previous iteration's frag reads done
#pragma unroll
            for (int i = 0; i < NA; ++i)
                GLD_LDS16(aG[i] + koA, As + (w * NA + i) * 512);
#pragma unroll
            for (int i = 0; i < NB; ++i)
                GLD_LDS16(bG[i] + koB, Bs + (w * NB + i) * 512);
            __syncthreads();             // staging (vmcnt) drained

            short8 af[FM], bf[FN];
#pragma unroll
            for (int fm = 0; fm < FM; ++fm)
                af[fm] = *(const short8*)&As[((wm * FM + fm) * 16 + l15) * 32 + sw];
#pragma unroll
            for (int fn = 0; fn < FN; ++fn)
                bf[fn] = *(const short8*)&Bs[((wn * FN + fn) * 16 + l15) * 32 + sw];
#pragma unroll
            for (int fm = 0; fm < FM; ++fm)
#pragma unroll
                for (int fn = 0; fn < FN; ++fn)
                    acc[fm][fn] = __builtin_amdgcn_mfma_f32_16x16x32_bf16(
                        af[fm], bf[fn], acc[fm][fn], 0, 0, 0);
        }
    }

    // epilogue: C/D layout col = lane&15, row = (lane>>4)*4 + reg
#pragma unroll
    for (int fm = 0; fm < FM; ++fm)
#pragma unroll
        for (int fn = 0; fn < FN; ++fn) {
            int col = n0 + (wn * FN + fn) * 16 + l15;
            float bv = bias[col];
#pragma unroll
            for (int r = 0; r < 4; ++r) {
                int row = m0 + (wm * FM + fm) * 16 + quad * 4 + r;
                C[(size_t)row * N + col] = acc[fm][fn][r] + bv;
            }
        }
}

// ---------------------------------------------------------------------------
// prep_qkv (unchanged, passing): RoPE + 1/8 q-scale + bf16 hi/lo split,
// Q/K: [bh][t][64], V: [bh][d][2048] transposed.
// ---------------------------------------------------------------------------
__global__ __launch_bounds__(256) void prep_qkv(
    const float* __restrict__ qkv,
    unsigned short* __restrict__ Qh, unsigned short* __restrict__ Ql,
    unsigned short* __restrict__ Kh, unsigned short* __restrict__ Kl,
    unsigned short* __restrict__ Vh, unsigned short* __restrict__ Vl)
{
    __shared__ float vt[64][65];
    const int tid = threadIdx.x;
    const int lin = blockIdx.x;
    const int tt = lin & 31, bh = lin >> 5;
    const int b = bh >> 4, h = bh & 15;
    const int r = tid >> 2;
    const int dblk = (tid & 3) * 16;
    const int tg = tt * 64 + r;
    const size_t src = (size_t)(b * SEQ + tg) * 3072 + h * 64 + dblk;
    const size_t dst = ((size_t)bh * SEQ + tg) * 64 + dblk;

    float q[16], k[16], v[16];
#pragma unroll
    for (int i = 0; i < 4; ++i) {
        *(float4*)&q[4 * i] = *(const float4*)(qkv + src + 4 * i);
        *(float4*)&k[4 * i] = *(const float4*)(qkv + src + 1024 + 4 * i);
        *(float4*)&v[4 * i] = *(const float4*)(qkv + src + 2048 + 4 * i);
    }
#pragma unroll
    for (int j = 0; j < 16; j += 2) {
        int pr = (dblk + j) >> 1;
        double e = (double)(2 * pr) / 64.0;
        float inv = (float)exp2(-e * 13.287712379549449);
        float ang = (float)tg * inv;
        float s, c;
        __sincosf(ang, &s, &c);
        float qe = q[j], qo = q[j + 1];
        q[j] = qe * c - qo * s; q[j + 1] = qe * s + qo * c;
        float ke = k[j], ko = k[j + 1];
        k[j] = ke * c - ko * s; k[j + 1] = ke * s + ko * c;
    }
    uint32_t ph[8], pl[8];
#pragma unroll
    for (int j = 0; j < 8; ++j) {
        float f0 = q[2 * j] * 0.125f, f1 = q[2 * j + 1] * 0.125f;
        unsigned short h0 = f2bf(f0), h1 = f2bf(f1);
        ph[j] = (uint32_t)h0 | ((uint32_t)h1 << 16);
        pl[j] = (uint32_t)f2bf(f0 - bf2f(h0)) | ((uint32_t)f2bf(f1 - bf2f(h1)) << 16);
    }
    *(uint4*)(Qh + dst) = *(uint4*)&ph[0]; *(uint4*)(Qh + dst + 8) = *(uint4*)&ph[4];
    *(uint4*)(Ql + dst) = *(uint4*)&pl[0]; *(uint4*)(Ql + dst + 8) = *(uint4*)&pl[4];
#pragma unroll
    for (int j = 0; j < 8; ++j) {
        float f0 = k[2 * j], f1 = k[2 * j + 1];
        unsigned short h0 = f2bf(f0), h1 = f2bf(f1);
        ph[j] = (uint32_t)h0 | ((uint32_t)h1 << 16);
        pl[j] = (uint32_t)f2bf(f0 - bf2f(h0)) | ((uint32_t)f2bf(f1 - bf2f(h1)) << 16);
    }
    *(uint4*)(Kh + dst) = *(uint4*)&ph[0]; *(uint4*)(Kh + dst + 8) = *(uint4*)&ph[4];
    *(uint4*)(Kl + dst) = *(uint4*)&pl[0]; *(uint4*)(Kl + dst + 8) = *(uint4*)&pl[4];

#pragma unroll
    for (int j = 0; j < 16; ++j) vt[r][dblk + j] = v[j];
    __syncthreads();
    const int d2 = tid >> 2;
    const int tb = (tid & 3) * 16;
#pragma unroll
    for (int j = 0; j < 8; ++j) {
        float f0 = vt[tb + 2 * j][d2], f1 = vt[tb + 2 * j + 1][d2];
        unsigned short h0 = f2bf(f0), h1 = f2bf(f1);
        ph[j] = (uint32_t)h0 | ((uint32_t)h1 << 16);
        pl[j] = (uint32_t)f2bf(f0 - bf2f(h0)) | ((uint32_t)f2bf(f1 - bf2f(h1)) << 16);
    }
    const size_t vdst = ((size_t)bh * 64 + d2) * SEQ + tt * 64 + tb;
    *(uint4*)(Vh + vdst) = *(uint4*)&ph[0]; *(uint4*)(Vh + vdst + 8) = *(uint4*)&ph[4];
    *(uint4*)(Vl + vdst) = *(uint4*)&pl[0]; *(uint4*)(Vl + vdst + 8) = *(uint4*)&pl[4];
}

// ---------------------------------------------------------------------------
// MFMA flash attention (unchanged from R4, passing).
// ---------------------------------------------------------------------------
#define LDR 72

__global__ __launch_bounds__(256, 2) void flash_mfma(
    const unsigned short* __restrict__ Qh, const unsigned short* __restrict__ Ql,
    const unsigned short* __restrict__ Kh, const unsigned short* __restrict__ Kl,
    const unsigned short* __restrict__ Vh, const unsigned short* __restrict__ Vl,
    const int* __restrict__ am, unsigned short* __restrict__ attnx)
{
    __shared__ __align__(16) unsigned short sKh[64 * LDR];
    __shared__ __align__(16) unsigned short sKl[64 * LDR];
    __shared__ __align__(16) unsigned short sVh[64 * LDR];
    __shared__ __align__(16) unsigned short sVl[64 * LDR];
    __shared__ __align__(16) unsigned short sP[4 * 16 * LDR];

    const int tid = threadIdx.x;
    const int lane = tid & 63, w = tid >> 6;
    const int l15 = lane & 15, quad = lane >> 4;
    const int lin = blockIdx.x;
    const int bh = lin & 31;
    const int p = lin >> 5;
    const int b = bh >> 4, h = bh & 15;
    unsigned short* pbase = sP + w * (16 * LDR);

#pragma unroll
    for (int phase = 0; phase < 2; ++phase) {
        const int qt = phase ? (31 - p) : p;

        const size_t qb = ((size_t)bh * SEQ + qt * 64 + w * 16 + l15) * 64 + quad * 8;
        const short8 qh0 = *(const short8*)(Qh + qb);
        const short8 qh1 = *(const short8*)(Qh + qb + 32);
        const short8 ql0 = *(const short8*)(Ql + qb);
        const short8 ql1 = *(const short8*)(Ql + qb + 32);

        floatx4 O[4];
        float m_[4], l_[4];
#pragma unroll
        for (int nf = 0; nf < 4; ++nf) O[nf] = (floatx4)0.f;
#pragma unroll
        for (int r = 0; r < 4; ++r) { m_[r] = -INFINITY; l_[r] = 0.f; }

        const int ktiles = qt + 1;
        for (int kt = 0; kt < ktiles; ++kt) {
            __syncthreads();
#pragma unroll
            for (int i = 0; i < 2; ++i) {
                const int u = tid + i * 256;
                const int row = u >> 3, blk = u & 7;
                const size_t kg = ((size_t)bh * SEQ + kt * 64 + row) * 64 + blk * 8;
                const size_t vg = ((size_t)bh * 64 + row) * SEQ + kt * 64 + blk * 8;
                const uint4 a0 = *(const uint4*)(Kh + kg);
                const uint4 a1 = *(const uint4*)(Kl + kg);
                const uint4 a2 = *(const uint4*)(Vh + vg);
                const uint4 a3 = *(const uint4*)(Vl + vg);
                const int lo = row * LDR + blk * 8;
                *(uint4*)&sKh[lo] = a0;
                *(uint4*)&sKl[lo] = a1;
                *(uint4*)&sVh[lo] = a2;
                *(uint4*)&sVl[lo] = a3;
            }
            __syncthreads();

            floatx4 S[4];
#pragma unroll
            for (int nf = 0; nf < 4; ++nf) {
                const int kb = (nf * 16 + l15) * LDR + quad * 8;
                const short8 kh0 = *(const short8*)&sKh[kb];
                const short8 kh1 = *(const short8*)&sKh[kb + 32];
                const short8 kl0 = *(const short8*)&sKl[kb];
                const short8 kl1 = *(const short8*)&sKl[kb + 32];
                floatx4 s = (floatx4)0.f;
                s = __builtin_amdgcn_mfma_f32_16x16x32_bf16(qh0, kh0, s, 0, 0, 0);
                s = __builtin_amdgcn_mfma_f32_16x16x32_bf16(qh1, kh1, s, 0, 0, 0);
                s = __builtin_amdgcn_mfma_f32_16x16x32_bf16(qh0, kl0, s, 0, 0, 0);
                s = __builtin_amdgcn_mfma_f32_16x16x32_bf16(qh1, kl1, s, 0, 0, 0);
                s = __builtin_amdgcn_mfma_f32_16x16x32_bf16(ql0, kh0, s, 0, 0, 0);
                s = __builtin_amdgcn_mfma_f32_16x16x32_bf16(ql1, kh1, s, 0, 0, 0);
                S[nf] = s;
            }

#pragma unroll
            for (int nf = 0; nf < 4; ++nf) {
                const int colg = kt * 64 + nf * 16 + l15;
                const bool amok = am[b * SEQ + colg] != 0;
#pragma unroll
                for (int r = 0; r < 4; ++r) {
                    const int rowg = qt * 64 + w * 16 + quad * 4 + r;
                    if (!amok || colg > rowg) S[nf][r] = -INFINITY;
                }
            }

            float alpha[4];
#pragma unroll
            for (int r = 0; r < 4; ++r) {
                float mx = fmaxf(fmaxf(S[0][r], S[1][r]), fmaxf(S[2][r], S[3][r]));
                mx = fmaxf(mx, __shfl_xor(mx, 1));
                mx = fmaxf(mx, __shfl_xor(mx, 2));
                mx = fmaxf(mx, __shfl_xor(mx, 4));
                mx = fmaxf(mx, __shfl_xor(mx, 8));
                const float mnew = fmaxf(m_[r], mx);
                float a, pv[4];
                if (mnew == -INFINITY) {
                    a = 1.f; pv[0] = pv[1] = pv[2] = pv[3] = 0.f;
                } else {
                    a = __expf(m_[r] - mnew);
#pragma unroll
                    for (int nf = 0; nf < 4; ++nf) pv[nf] = __expf(S[nf][r] - mnew);
                }
                float rs = pv[0] + pv[1] + pv[2] + pv[3];
                rs += __shfl_xor(rs, 1);
                rs += __shfl_xor(rs, 2);
                rs += __shfl_xor(rs, 4);
                rs += __shfl_xor(rs, 8);
                l_[r] = l_[r] * a + rs;
                m_[r] = mnew;
                alpha[r] = a;
#pragma unroll
                for (int nf = 0; nf < 4; ++nf)
                    pbase[(quad * 4 + r) * LDR + nf * 16 + l15] = f2bf(pv[nf]);
            }
#pragma unroll
            for (int nf = 0; nf < 4; ++nf)
#pragma unroll
                for (int r = 0; r < 4; ++r) O[nf][r] *= alpha[r];

            const short8 pf0 = *(const short8*)(pbase + l15 * LDR + quad * 8);
            const short8 pf1 = *(const short8*)(pbase + l15 * LDR + 32 + quad * 8);
#pragma unroll
            for (int nf = 0; nf < 4; ++nf) {
                const int vb = (nf * 16 + l15) * LDR + quad * 8;
                const short8 vh0 = *(const short8*)&sVh[vb];
                const short8 vh1 = *(const short8*)&sVh[vb + 32];
                const short8 vl0 = *(const short8*)&sVl[vb];
                const short8 vl1 = *(const short8*)&sVl[vb + 32];
                floatx4 o = O[nf];
                o = __builtin_amdgcn_mfma_f32_16x16x32_bf16(pf0, vh0, o, 0, 0, 0);
                o = __builtin_amdgcn_mfma_f32_16x16x32_bf16(pf1, vh1, o, 0, 0, 0);
                o = __builtin_amdgcn_mfma_f32_16x16x32_bf16(pf0, vl0, o, 0, 0, 0);
                o = __builtin_amdgcn_mfma_f32_16x16x32_bf16(pf1, vl1, o, 0, 0, 0);
                O[nf] = o;
            }
        }

        float rl[4];
#pragma unroll
        for (int r = 0; r < 4; ++r) rl[r] = 1.0f / l_[r];
#pragma unroll
        for (int nf = 0; nf < 4; ++nf)
#pragma unroll
            for (int r = 0; r < 4; ++r) {
                const int tok = b * SEQ + qt * 64 + w * 16 + quad * 4 + r;
                const int col = h * 64 + nf * 16 + l15;
                const float val = O[nf][r] * rl[r];
                const unsigned short hi = f2bf(val);
                const unsigned short lo = f2bf(val - bf2f(hi));
                attnx[(size_t)tok * 2048 + col] = hi;
                attnx[(size_t)tok * 2048 + 1024 + col] = lo;
            }
    }
}

// ---------------------------------------------------------------------------
extern "C" void kernel_launch(void* const* d_in, const int* in_sizes, int n_in,
                              void* d_out, int out_size, void* d_ws, size_t ws_size,
                              hipStream_t stream)
{
    const float* x    = (const float*)d_in[0];
    const int*   am   = (const int*)d_in[1];
    const float* Wqkv = (const float*)d_in[2];
    const float* bqkv = (const float*)d_in[3];
    const float* Wout = (const float*)d_in[4];
    const float* bout = (const float*)d_in[5];
    float* out = (float*)d_out;

    // ws layout (113.2 MB, same footprint as R4):
    //   Bt 12.58MB | qkv fp32 50.33MB (reused as attnx bf16 after prep) |
    //   Qh Ql Kh Kl Vh Vl 8.39MB each (Vh+Vl doubles as Ax before prep)
    char* ws = (char*)d_ws;
    unsigned short* Bt = (unsigned short*)ws;
    float* qkv = (float*)(ws + 12582912);
    unsigned short* attnx = (unsigned short*)qkv;        // alias: qkv dead after prep
    unsigned short* Qh = (unsigned short*)(ws + 62914560);
    unsigned short* Ql = Qh + 4194304;
    unsigned short* Kh = Ql + 4194304;
    unsigned short* Kl = Kh + 4194304;
    unsigned short* Vh = Kl + 4194304;
    unsigned short* Vl = Vh + 4194304;
    unsigned short* Ax = Vh;                             // alias: dead after gemm1

    // 0) split x -> bf16 hi|lo
    split_a<<<4096, 256, 0, stream>>>(x, Ax);

    // 1) qkv = x @ W_qkv + b   (pure-bf16 MFMA, swizzled LDS, DMA staging)
    split_w_t<<<dim3(96, 32), 256, 0, stream>>>(Wqkv, 3072, Bt);
    gemm_mfma_x3<2, 2, 4, 4><<<dim3(24, 32), 256, 0, stream>>>(
        Ax, Bt, bqkv, qkv, TOKENS, 3072);

    // 2) RoPE + scale + split + V transpose (overwrites Ax region - ordered)
    prep_qkv<<<1024, 256, 0, stream>>>(qkv, Qh, Ql, Kh, Kl, Vh, Vl);

    // 3) MFMA flash attention -> attnx (bf16 hi|lo, into dead qkv region)
    flash_mfma<<<512, 256, 0, stream>>>(Qh, Ql, Kh, Kl, Vh, Vl, am, attnx);

    // 4) out = attn @ W_out + b
    split_w_t<<<dim3(32, 32), 256, 0, stream>>>(Wout, 1024, Bt);
    gemm_mfma_x3<2, 2, 2, 4><<<dim3(8, 64), 256, 0, stream>>>(
        attnx, Bt, bout, out, TOKENS, 1024);
}

// Round 6
// 333.984 us; speedup vs baseline: 3.6696x; 1.1350x over previous
//
#include <hip/hip_runtime.h>
#include <math.h>
#include <stdint.h>

#define D_MODEL 1024
#define N_HEADS 16
#define HEAD_DIM 64
#define BATCH 2
#define SEQ 2048
#define TOKENS (BATCH * SEQ)   // 4096

typedef __attribute__((ext_vector_type(8))) short short8;   // 8 bf16 = 4 VGPRs
typedef __attribute__((ext_vector_type(4))) float floatx4;  // MFMA C/D frag

__device__ __forceinline__ unsigned short f2bf(float f) {
    uint32_t u = __float_as_uint(f);
    u += 0x7fffu + ((u >> 16) & 1u);
    return (unsigned short)(u >> 16);
}
__device__ __forceinline__ float bf2f(unsigned short h) {
    return __uint_as_float(((uint32_t)h) << 16);
}

// async global -> LDS, 16B per lane; LDS dest = wave-uniform base + lane*16
#define GLD_LDS16(gp, lp) __builtin_amdgcn_global_load_lds(                 \
    (const __attribute__((address_space(1))) void*)(gp),                    \
    (__attribute__((address_space(3))) void*)(lp), 16, 0, 0)

// ---------------------------------------------------------------------------
// split_a: X fp32 [rows][1024] -> Ax bf16 [rows][2048] (hi | lo along k)
// ---------------------------------------------------------------------------
__global__ __launch_bounds__(256) void split_a(
    const float* __restrict__ X, unsigned short* __restrict__ Ax)
{
    const int idx = blockIdx.x * 256 + threadIdx.x;
    const int row = idx >> 8;            // 256 threads cover one 1024-row
    const int c = (idx & 255) * 4;
    float4 v = *(const float4*)(X + (size_t)row * 1024 + c);
    float f[4] = {v.x, v.y, v.z, v.w};
    uint32_t hp[2], lp[2];
#pragma unroll
    for (int j = 0; j < 2; ++j) {
        unsigned short h0 = f2bf(f[2 * j]), h1 = f2bf(f[2 * j + 1]);
        hp[j] = (uint32_t)h0 | ((uint32_t)h1 << 16);
        lp[j] = (uint32_t)f2bf(f[2 * j] - bf2f(h0)) |
                ((uint32_t)f2bf(f[2 * j + 1] - bf2f(h1)) << 16);
    }
    *(uint2*)(Ax + (size_t)row * 2048 + c) = make_uint2(hp[0], hp[1]);
    *(uint2*)(Ax + (size_t)row * 2048 + 1024 + c) = make_uint2(lp[0], lp[1]);
}

// ---------------------------------------------------------------------------
// Weight transpose + bf16 hi/lo split (unchanged, passing)
// ---------------------------------------------------------------------------
__global__ __launch_bounds__(256) void split_w_t(
    const float* __restrict__ W, int N, unsigned short* __restrict__ Bt)
{
    __shared__ float t[32][33];
    const int tid = threadIdx.x;
    const int n0 = blockIdx.x * 32, k0 = blockIdx.y * 32;
    const int c = tid & 31, r = tid >> 5;
#pragma unroll
    for (int i = 0; i < 4; ++i)
        t[r + 8 * i][c] = W[(size_t)(k0 + r + 8 * i) * N + n0 + c];
    __syncthreads();
#pragma unroll
    for (int i = 0; i < 4; ++i) {
        int dn = r + 8 * i;
        float f = t[c][dn];
        unsigned short hi = f2bf(f);
        unsigned short lo = f2bf(f - bf2f(hi));
        size_t row = (size_t)(n0 + dn) * 2048;
        Bt[row + k0 + c] = hi;
        Bt[row + 1024 + k0 + c] = lo;
    }
}

// ---------------------------------------------------------------------------
// FUSED x3 bf16 MFMA GEMM: one K-pass, Ah/Al/Bh/Bl tiles staged together,
// 3 products (Ah*Bh + Ah*Bl + Al*Bh) per K-step into one accumulator.
// vs R5: 3x fewer barriers, 3x fewer HBM fetches, 48 MFMA per barrier-pair.
// LDS swizzle from R5 kept (0 bank conflicts): staging lane L takes k-chunk
// (L&3)^((L>>3)&3); fragment (l15,quad) reads slot offset (quad^((l15>>1)&3)).
// ---------------------------------------------------------------------------
template<int WM, int WN, int FM, int FN>
__global__ __launch_bounds__(256) void gemm_mfma_x3f(
    const unsigned short* __restrict__ Ax, const unsigned short* __restrict__ Bt,
    const float* __restrict__ bias, float* __restrict__ C, int M, int N)
{
    constexpr int BM = WM * FM * 16;
    constexpr int BN = WN * FN * 16;
    constexpr int NA = BM / 64;          // GLD instrs per wave per A buffer
    constexpr int NB = BN / 64;

    __shared__ __align__(16) unsigned short sAh[BM * 32];
    __shared__ __align__(16) unsigned short sAl[BM * 32];
    __shared__ __align__(16) unsigned short sBh[BN * 32];
    __shared__ __align__(16) unsigned short sBl[BN * 32];

    const int tid = threadIdx.x;
    const int w = tid >> 6, lane = tid & 63;
    const int l15 = lane & 15, quad = lane >> 4;
    const int wm = w / WN, wn = w % WN;
    const int m0 = blockIdx.y * BM, n0 = blockIdx.x * BN;

    const int ch = (lane & 3) ^ ((lane >> 3) & 3);       // staging swizzle
    const int sw = (quad ^ ((l15 >> 1) & 3)) * 8;        // frag-read swizzle

    const unsigned short* aG[NA];
    const unsigned short* bG[NB];
#pragma unroll
    for (int i = 0; i < NA; ++i)
        aG[i] = Ax + (size_t)(m0 + (w * NA + i) * 16 + (lane >> 2)) * 2048
                   + ch * 8;
#pragma unroll
    for (int i = 0; i < NB; ++i)
        bG[i] = Bt + (size_t)(n0 + (w * NB + i) * 16 + (lane >> 2)) * 2048
                   + ch * 8;

    floatx4 acc[FM][FN];
#pragma unroll
    for (int fm = 0; fm < FM; ++fm)
#pragma unroll
        for (int fn = 0; fn < FN; ++fn) acc[fm][fn] = (floatx4)0.f;

    for (int ks = 0; ks < 32; ++ks) {
        const int ko = ks * 32;          // hi at ko, lo at 1024+ko
        __syncthreads();                 // previous iteration's frag reads done
#pragma unroll
        for (int i = 0; i < NA; ++i) {
            GLD_LDS16(aG[i] + ko,        sAh + (w * NA + i) * 512);
            GLD_LDS16(aG[i] + 1024 + ko, sAl + (w * NA + i) * 512);
        }
#pragma unroll
        for (int i = 0; i < NB; ++i) {
            GLD_LDS16(bG[i] + ko,        sBh + (w * NB + i) * 512);
            GLD_LDS16(bG[i] + 1024 + ko, sBl + (w * NB + i) * 512);
        }
        __syncthreads();                 // staging (vmcnt) drained

        short8 ah[FM], al[FM], bh[FN], bl[FN];
#pragma unroll
        for (int fm = 0; fm < FM; ++fm) {
            const int off = ((wm * FM + fm) * 16 + l15) * 32 + sw;
            ah[fm] = *(const short8*)&sAh[off];
            al[fm] = *(const short8*)&sAl[off];
        }
#pragma unroll
        for (int fn = 0; fn < FN; ++fn) {
            const int off = ((wn * FN + fn) * 16 + l15) * 32 + sw;
            bh[fn] = *(const short8*)&sBh[off];
            bl[fn] = *(const short8*)&sBl[off];
        }
#pragma unroll
        for (int fm = 0; fm < FM; ++fm)
#pragma unroll
            for (int fn = 0; fn < FN; ++fn) {
                floatx4 a = acc[fm][fn];
                a = __builtin_amdgcn_mfma_f32_16x16x32_bf16(ah[fm], bh[fn], a, 0, 0, 0);
                a = __builtin_amdgcn_mfma_f32_16x16x32_bf16(ah[fm], bl[fn], a, 0, 0, 0);
                a = __builtin_amdgcn_mfma_f32_16x16x32_bf16(al[fm], bh[fn], a, 0, 0, 0);
                acc[fm][fn] = a;
            }
    }

    // epilogue: C/D layout col = lane&15, row = (lane>>4)*4 + reg
#pragma unroll
    for (int fm = 0; fm < FM; ++fm)
#pragma unroll
        for (int fn = 0; fn < FN; ++fn) {
            int col = n0 + (wn * FN + fn) * 16 + l15;
            float bv = bias[col];
#pragma unroll
            for (int r = 0; r < 4; ++r) {
                int row = m0 + (wm * FM + fm) * 16 + quad * 4 + r;
                C[(size_t)row * N + col] = acc[fm][fn][r] + bv;
            }
        }
}

// ---------------------------------------------------------------------------
// prep_qkv (unchanged, passing): RoPE + 1/8 q-scale + bf16 hi/lo split,
// Q/K: [bh][t][64], V: [bh][d][2048] transposed.
// ---------------------------------------------------------------------------
__global__ __launch_bounds__(256) void prep_qkv(
    const float* __restrict__ qkv,
    unsigned short* __restrict__ Qh, unsigned short* __restrict__ Ql,
    unsigned short* __restrict__ Kh, unsigned short* __restrict__ Kl,
    unsigned short* __restrict__ Vh, unsigned short* __restrict__ Vl)
{
    __shared__ float vt[64][65];
    const int tid = threadIdx.x;
    const int lin = blockIdx.x;
    const int tt = lin & 31, bh = lin >> 5;
    const int b = bh >> 4, h = bh & 15;
    const int r = tid >> 2;
    const int dblk = (tid & 3) * 16;
    const int tg = tt * 64 + r;
    const size_t src = (size_t)(b * SEQ + tg) * 3072 + h * 64 + dblk;
    const size_t dst = ((size_t)bh * SEQ + tg) * 64 + dblk;

    float q[16], k[16], v[16];
#pragma unroll
    for (int i = 0; i < 4; ++i) {
        *(float4*)&q[4 * i] = *(const float4*)(qkv + src + 4 * i);
        *(float4*)&k[4 * i] = *(const float4*)(qkv + src + 1024 + 4 * i);
        *(float4*)&v[4 * i] = *(const float4*)(qkv + src + 2048 + 4 * i);
    }
#pragma unroll
    for (int j = 0; j < 16; j += 2) {
        int pr = (dblk + j) >> 1;
        double e = (double)(2 * pr) / 64.0;
        float inv = (float)exp2(-e * 13.287712379549449);
        float ang = (float)tg * inv;
        float s, c;
        __sincosf(ang, &s, &c);
        float qe = q[j], qo = q[j + 1];
        q[j] = qe * c - qo * s; q[j + 1] = qe * s + qo * c;
        float ke = k[j], ko = k[j + 1];
        k[j] = ke * c - ko * s; k[j + 1] = ke * s + ko * c;
    }
    uint32_t ph[8], pl[8];
#pragma unroll
    for (int j = 0; j < 8; ++j) {
        float f0 = q[2 * j] * 0.125f, f1 = q[2 * j + 1] * 0.125f;
        unsigned short h0 = f2bf(f0), h1 = f2bf(f1);
        ph[j] = (uint32_t)h0 | ((uint32_t)h1 << 16);
        pl[j] = (uint32_t)f2bf(f0 - bf2f(h0)) | ((uint32_t)f2bf(f1 - bf2f(h1)) << 16);
    }
    *(uint4*)(Qh + dst) = *(uint4*)&ph[0]; *(uint4*)(Qh + dst + 8) = *(uint4*)&ph[4];
    *(uint4*)(Ql + dst) = *(uint4*)&pl[0]; *(uint4*)(Ql + dst + 8) = *(uint4*)&pl[4];
#pragma unroll
    for (int j = 0; j < 8; ++j) {
        float f0 = k[2 * j], f1 = k[2 * j + 1];
        unsigned short h0 = f2bf(f0), h1 = f2bf(f1);
        ph[j] = (uint32_t)h0 | ((uint32_t)h1 << 16);
        pl[j] = (uint32_t)f2bf(f0 - bf2f(h0)) | ((uint32_t)f2bf(f1 - bf2f(h1)) << 16);
    }
    *(uint4*)(Kh + dst) = *(uint4*)&ph[0]; *(uint4*)(Kh + dst + 8) = *(uint4*)&ph[4];
    *(uint4*)(Kl + dst) = *(uint4*)&pl[0]; *(uint4*)(Kl + dst + 8) = *(uint4*)&pl[4];

#pragma unroll
    for (int j = 0; j < 16; ++j) vt[r][dblk + j] = v[j];
    __syncthreads();
    const int d2 = tid >> 2;
    const int tb = (tid & 3) * 16;
#pragma unroll
    for (int j = 0; j < 8; ++j) {
        float f0 = vt[tb + 2 * j][d2], f1 = vt[tb + 2 * j + 1][d2];
        unsigned short h0 = f2bf(f0), h1 = f2bf(f1);
        ph[j] = (uint32_t)h0 | ((uint32_t)h1 << 16);
        pl[j] = (uint32_t)f2bf(f0 - bf2f(h0)) | ((uint32_t)f2bf(f1 - bf2f(h1)) << 16);
    }
    const size_t vdst = ((size_t)bh * 64 + d2) * SEQ + tt * 64 + tb;
    *(uint4*)(Vh + vdst) = *(uint4*)&ph[0]; *(uint4*)(Vh + vdst + 8) = *(uint4*)&ph[4];
    *(uint4*)(Vl + vdst) = *(uint4*)&pl[0]; *(uint4*)(Vl + vdst + 8) = *(uint4*)&pl[4];
}

// ---------------------------------------------------------------------------
// MFMA flash attention (unchanged from R5, passing).
// ---------------------------------------------------------------------------
#define LDR 72

__global__ __launch_bounds__(256, 2) void flash_mfma(
    const unsigned short* __restrict__ Qh, const unsigned short* __restrict__ Ql,
    const unsigned short* __restrict__ Kh, const unsigned short* __restrict__ Kl,
    const unsigned short* __restrict__ Vh, const unsigned short* __restrict__ Vl,
    const int* __restrict__ am, unsigned short* __restrict__ attnx)
{
    __shared__ __align__(16) unsigned short sKh[64 * LDR];
    __shared__ __align__(16) unsigned short sKl[64 * LDR];
    __shared__ __align__(16) unsigned short sVh[64 * LDR];
    __shared__ __align__(16) unsigned short sVl[64 * LDR];
    __shared__ __align__(16) unsigned short sP[4 * 16 * LDR];

    const int tid = threadIdx.x;
    const int lane = tid & 63, w = tid >> 6;
    const int l15 = lane & 15, quad = lane >> 4;
    const int lin = blockIdx.x;
    const int bh = lin & 31;
    const int p = lin >> 5;
    const int b = bh >> 4, h = bh & 15;
    unsigned short* pbase = sP + w * (16 * LDR);

#pragma unroll
    for (int phase = 0; phase < 2; ++phase) {
        const int qt = phase ? (31 - p) : p;

        const size_t qb = ((size_t)bh * SEQ + qt * 64 + w * 16 + l15) * 64 + quad * 8;
        const short8 qh0 = *(const short8*)(Qh + qb);
        const short8 qh1 = *(const short8*)(Qh + qb + 32);
        const short8 ql0 = *(const short8*)(Ql + qb);
        const short8 ql1 = *(const short8*)(Ql + qb + 32);

        floatx4 O[4];
        float m_[4], l_[4];
#pragma unroll
        for (int nf = 0; nf < 4; ++nf) O[nf] = (floatx4)0.f;
#pragma unroll
        for (int r = 0; r < 4; ++r) { m_[r] = -INFINITY; l_[r] = 0.f; }

        const int ktiles = qt + 1;
        for (int kt = 0; kt < ktiles; ++kt) {
            __syncthreads();
#pragma unroll
            for (int i = 0; i < 2; ++i) {
                const int u = tid + i * 256;
                const int row = u >> 3, blk = u & 7;
                const size_t kg = ((size_t)bh * SEQ + kt * 64 + row) * 64 + blk * 8;
                const size_t vg = ((size_t)bh * 64 + row) * SEQ + kt * 64 + blk * 8;
                const uint4 a0 = *(const uint4*)(Kh + kg);
                const uint4 a1 = *(const uint4*)(Kl + kg);
                const uint4 a2 = *(const uint4*)(Vh + vg);
                const uint4 a3 = *(const uint4*)(Vl + vg);
                const int lo = row * LDR + blk * 8;
                *(uint4*)&sKh[lo] = a0;
                *(uint4*)&sKl[lo] = a1;
                *(uint4*)&sVh[lo] = a2;
                *(uint4*)&sVl[lo] = a3;
            }
            __syncthreads();

            floatx4 S[4];
#pragma unroll
            for (int nf = 0; nf < 4; ++nf) {
                const int kb = (nf * 16 + l15) * LDR + quad * 8;
                const short8 kh0 = *(const short8*)&sKh[kb];
                const short8 kh1 = *(const short8*)&sKh[kb + 32];
                const short8 kl0 = *(const short8*)&sKl[kb];
                const short8 kl1 = *(const short8*)&sKl[kb + 32];
                floatx4 s = (floatx4)0.f;
                s = __builtin_amdgcn_mfma_f32_16x16x32_bf16(qh0, kh0, s, 0, 0, 0);
                s = __builtin_amdgcn_mfma_f32_16x16x32_bf16(qh1, kh1, s, 0, 0, 0);
                s = __builtin_amdgcn_mfma_f32_16x16x32_bf16(qh0, kl0, s, 0, 0, 0);
                s = __builtin_amdgcn_mfma_f32_16x16x32_bf16(qh1, kl1, s, 0, 0, 0);
                s = __builtin_amdgcn_mfma_f32_16x16x32_bf16(ql0, kh0, s, 0, 0, 0);
                s = __builtin_amdgcn_mfma_f32_16x16x32_bf16(ql1, kh1, s, 0, 0, 0);
                S[nf] = s;
            }

#pragma unroll
            for (int nf = 0; nf < 4; ++nf) {
                const int colg = kt * 64 + nf * 16 + l15;
                const bool amok = am[b * SEQ + colg] != 0;
#pragma unroll
                for (int r = 0; r < 4; ++r) {
                    const int rowg = qt * 64 + w * 16 + quad * 4 + r;
                    if (!amok || colg > rowg) S[nf][r] = -INFINITY;
                }
            }

            float alpha[4];
#pragma unroll
            for (int r = 0; r < 4; ++r) {
                float mx = fmaxf(fmaxf(S[0][r], S[1][r]), fmaxf(S[2][r], S[3][r]));
                mx = fmaxf(mx, __shfl_xor(mx, 1));
                mx = fmaxf(mx, __shfl_xor(mx, 2));
                mx = fmaxf(mx, __shfl_xor(mx, 4));
                mx = fmaxf(mx, __shfl_xor(mx, 8));
                const float mnew = fmaxf(m_[r], mx);
                float a, pv[4];
                if (mnew == -INFINITY) {
                    a = 1.f; pv[0] = pv[1] = pv[2] = pv[3] = 0.f;
                } else {
                    a = __expf(m_[r] - mnew);
#pragma unroll
                    for (int nf = 0; nf < 4; ++nf) pv[nf] = __expf(S[nf][r] - mnew);
                }
                float rs = pv[0] + pv[1] + pv[2] + pv[3];
                rs += __shfl_xor(rs, 1);
                rs += __shfl_xor(rs, 2);
                rs += __shfl_xor(rs, 4);
                rs += __shfl_xor(rs, 8);
                l_[r] = l_[r] * a + rs;
                m_[r] = mnew;
                alpha[r] = a;
#pragma unroll
                for (int nf = 0; nf < 4; ++nf)
                    pbase[(quad * 4 + r) * LDR + nf * 16 + l15] = f2bf(pv[nf]);
            }
#pragma unroll
            for (int nf = 0; nf < 4; ++nf)
#pragma unroll
                for (int r = 0; r < 4; ++r) O[nf][r] *= alpha[r];

            const short8 pf0 = *(const short8*)(pbase + l15 * LDR + quad * 8);
            const short8 pf1 = *(const short8*)(pbase + l15 * LDR + 32 + quad * 8);
#pragma unroll
            for (int nf = 0; nf < 4; ++nf) {
                const int vb = (nf * 16 + l15) * LDR + quad * 8;
                const short8 vh0 = *(const short8*)&sVh[vb];
                const short8 vh1 = *(const short8*)&sVh[vb + 32];
                const short8 vl0 = *(const short8*)&sVl[vb];
                const short8 vl1 = *(const short8*)&sVl[vb + 32];
                floatx4 o = O[nf];
                o = __builtin_amdgcn_mfma_f32_16x16x32_bf16(pf0, vh0, o, 0, 0, 0);
                o = __builtin_amdgcn_mfma_f32_16x16x32_bf16(pf1, vh1, o, 0, 0, 0);
                o = __builtin_amdgcn_mfma_f32_16x16x32_bf16(pf0, vl0, o, 0, 0, 0);
                o = __builtin_amdgcn_mfma_f32_16x16x32_bf16(pf1, vl1, o, 0, 0, 0);
                O[nf] = o;
            }
        }

        float rl[4];
#pragma unroll
        for (int r = 0; r < 4; ++r) rl[r] = 1.0f / l_[r];
#pragma unroll
        for (int nf = 0; nf < 4; ++nf)
#pragma unroll
            for (int r = 0; r < 4; ++r) {
                const int tok = b * SEQ + qt * 64 + w * 16 + quad * 4 + r;
                const int col = h * 64 + nf * 16 + l15;
                const float val = O[nf][r] * rl[r];
                const unsigned short hi = f2bf(val);
                const unsigned short lo = f2bf(val - bf2f(hi));
                attnx[(size_t)tok * 2048 + col] = hi;
                attnx[(size_t)tok * 2048 + 1024 + col] = lo;
            }
    }
}

// ---------------------------------------------------------------------------
extern "C" void kernel_launch(void* const* d_in, const int* in_sizes, int n_in,
                              void* d_out, int out_size, void* d_ws, size_t ws_size,
                              hipStream_t stream)
{
    const float* x    = (const float*)d_in[0];
    const int*   am   = (const int*)d_in[1];
    const float* Wqkv = (const float*)d_in[2];
    const float* bqkv = (const float*)d_in[3];
    const float* Wout = (const float*)d_in[4];
    const float* bout = (const float*)d_in[5];
    float* out = (float*)d_out;

    // ws layout (113.2 MB, unchanged):
    //   Bt 12.58MB | qkv fp32 50.33MB (reused as attnx bf16 after prep) |
    //   Qh Ql Kh Kl Vh Vl 8.39MB each (Vh+Vl doubles as Ax before prep)
    char* ws = (char*)d_ws;
    unsigned short* Bt = (unsigned short*)ws;
    float* qkv = (float*)(ws + 12582912);
    unsigned short* attnx = (unsigned short*)qkv;        // alias: qkv dead after prep
    unsigned short* Qh = (unsigned short*)(ws + 62914560);
    unsigned short* Ql = Qh + 4194304;
    unsigned short* Kh = Ql + 4194304;
    unsigned short* Kl = Kh + 4194304;
    unsigned short* Vh = Kl + 4194304;
    unsigned short* Vl = Vh + 4194304;
    unsigned short* Ax = Vh;                             // alias: dead after gemm1

    // 0) split x -> bf16 hi|lo
    split_a<<<4096, 256, 0, stream>>>(x, Ax);

    // 1) qkv = x @ W_qkv + b   (fused-x3 bf16 MFMA, swizzled LDS, DMA staging)
    split_w_t<<<dim3(96, 32), 256, 0, stream>>>(Wqkv, 3072, Bt);
    gemm_mfma_x3f<2, 2, 4, 4><<<dim3(24, 32), 256, 0, stream>>>(
        Ax, Bt, bqkv, qkv, TOKENS, 3072);

    // 2) RoPE + scale + split + V transpose (overwrites Ax region - ordered)
    prep_qkv<<<1024, 256, 0, stream>>>(qkv, Qh, Ql, Kh, Kl, Vh, Vl);

    // 3) MFMA flash attention -> attnx (bf16 hi|lo, into dead qkv region)
    flash_mfma<<<512, 256, 0, stream>>>(Qh, Ql, Kh, Kl, Vh, Vl, am, attnx);

    // 4) out = attn @ W_out + b
    split_w_t<<<dim3(32, 32), 256, 0, stream>>>(Wout, 1024, Bt);
    gemm_mfma_x3f<2, 2, 2, 4><<<dim3(8, 64), 256, 0, stream>>>(
        attnx, Bt, bout, out, TOKENS, 1024);
}